// Round 14
// baseline (164.920 us; speedup 1.0000x reference)
//
#include <hip/hip_runtime.h>
#include <hip/hip_bf16.h>
#include <math.h>

#define SS   1024
#define DM   1024
#define NH   16
#define DKH  64
#define NB   4
#define NBH  64

typedef unsigned short ush;
typedef unsigned int uint32;
typedef __attribute__((ext_vector_type(8))) short bf8_t;   // 8 bf16 = 4 VGPR
typedef __attribute__((ext_vector_type(4))) float f32x4;
#define MFMA16(a,b,c) __builtin_amdgcn_mfma_f32_16x16x32_bf16((a),(b),(c),0,0,0)

__device__ __forceinline__ ush f2bf(float x){ return __bfloat16_as_ushort(__float2bfloat16(x)); }
__device__ __forceinline__ float bf2f(ush h){ return __bfloat162float(__ushort_as_bfloat16(h)); }
__device__ __forceinline__ uint32 pk2(float a, float b){
  return (uint32)f2bf(a) | ((uint32)f2bf(b) << 16);
}
// pack value as (lo16<<16)|hi16
__device__ __forceinline__ uint32 pkhl(float v){
  ush h = f2bf(v);
  return (uint32)h | ((uint32)f2bf(v - bf2f(h)) << 16);
}
// extract hi/lo bf16 pairs from two interleaved uints (ulo = smaller d)
__device__ __forceinline__ uint32 prmh(uint32 uhi, uint32 ulo){
  return __builtin_amdgcn_perm(uhi, ulo, 0x05040100u);
}
__device__ __forceinline__ uint32 prml(uint32 uhi, uint32 ulo){
  return __builtin_amdgcn_perm(uhi, ulo, 0x07060302u);
}
// [rows][64]-ush tile, XOR swizzle on 16B chunks
__device__ __forceinline__ int swz8(int row, int chunk){
  return row*64 + (((chunk) ^ (row & 7)) << 3);
}
union U4B8 { uint4 u; bf8_t b; };

// ---- x fp32 -> bf16 (hi only)
__global__ __launch_bounds__(256) void xconv(
    const float* __restrict__ q, const float* __restrict__ k, const float* __restrict__ v,
    ush* __restrict__ xq, ush* __restrict__ xk, ush* __restrict__ xv)
{
  const float* src = (blockIdx.y==0)?q:(blockIdx.y==1)?k:v;
  ush* dst = (blockIdx.y==0)?xq:(blockIdx.y==1)?xk:xv;
  const size_t i = ((size_t)blockIdx.x*256 + threadIdx.x)*8;
  float4 a = *(const float4*)&src[i];
  float4 b = *(const float4*)&src[i+4];
  uint4 o;
  o.x = pk2(a.x, a.y); o.y = pk2(a.z, a.w);
  o.z = pk2(b.x, b.y); o.w = pk2(b.z, b.w);
  *(uint4*)&dst[i] = o;
}

// ---- weight convert: W (K x N) fp32 -> Wt (N x K) bf16 hi only
__global__ void wconv4(const float* __restrict__ W0, const float* __restrict__ W1,
                       const float* __restrict__ W2, const float* __restrict__ W3,
                       ush* __restrict__ H0, ush* __restrict__ H1,
                       ush* __restrict__ H2, ush* __restrict__ H3)
{
  __shared__ float T[32][33];
  const int tx = threadIdx.x, ty = threadIdx.y;    // (32,8)
  const int z = blockIdx.z;
  const float* W = (z==0)?W0:(z==1)?W1:(z==2)?W2:W3;
  ush* H = (z==0)?H0:(z==1)?H1:(z==2)?H2:H3;
  const int k0 = blockIdx.y*32, n0 = blockIdx.x*32;
  #pragma unroll
  for (int i = 0; i < 4; ++i){
    int r = ty + 8*i;
    T[r][tx] = W[(size_t)(k0 + r)*DM + n0 + tx];
  }
  __syncthreads();
  #pragma unroll
  for (int i = 0; i < 4; ++i){
    int r = ty + 8*i;              // n-local
    H[(size_t)(n0 + r)*DM + k0 + tx] = f2bf(T[tx][r]);
  }
}

// ---- fused Q/K/V projection: BK=32, 1-term (W hi), double-buffered LDS via
// global_load_lds width-16 with pre-swizzled per-lane SOURCE addresses.
__global__ __launch_bounds__(256) void proj_qkv(
    const ush* __restrict__ xq, const ush* __restrict__ xk, const ush* __restrict__ xv,
    const ush* __restrict__ Wqh, const ush* __restrict__ Wkh, const ush* __restrict__ Wvh,
    const float* __restrict__ bq, const float* __restrict__ bk,
    const float* __restrict__ bv,
    uint32* __restrict__ Qi, ush* __restrict__ Kb, ush* __restrict__ Vt)
{
  // staging: 2 buffers x (As 4096 | Bhs 4096) = 32 KB; V-epilogue 4*4224 ush
  __shared__ ush SMEM[16896];

  const int fid = blockIdx.x;
  const int glob = (fid & 7)*96 + (fid >> 3);  // XCD-contiguous chunks of 96
  const int z = glob >> 8, rem = glob & 255;
  const int m0 = (rem >> 3) * 128, n0 = (rem & 7) * 128;

  const ush* A  = (z==0) ? xq  : (z==1) ? xk  : xv;
  const ush* Bh = (z==0) ? Wqh : (z==1) ? Wkh : Wvh;

  const int tid = threadIdx.x;
  const int lane = tid & 63, w = tid >> 6;
  const int c = lane & 15, g = lane >> 4;
  const int wr = w >> 1, wc = w & 1;

  f32x4 acc[4][4];
  #pragma unroll
  for (int i = 0; i < 4; ++i)
    #pragma unroll
    for (int j = 0; j < 4; ++j) acc[i][j] = (f32x4){0.f,0.f,0.f,0.f};

  const int prow0 = w*16 + (lane >> 3), prow1 = prow0 + 8;
  const int jj = lane & 7;
  const int sg0 = jj ^ (prow0 & 7), sg1 = jj ^ (prow1 & 7);
  const size_t aoff0 = (size_t)(2*prow0 + (sg0 >> 2))*DM + (sg0 & 3)*8;
  const size_t aoff1 = (size_t)(2*prow1 + (sg1 >> 2))*DM + (sg1 & 3)*8;
  const ush* Aab = A  + (size_t)m0*DM;
  const ush* Bhb = Bh + (size_t)n0*DM;
  const int lb0 = w*1024, lb1 = w*1024 + 512;   // wave-uniform LDS bases (ush)

#define GLL(GP, LIDX) __builtin_amdgcn_global_load_lds( \
    (const __attribute__((address_space(1))) unsigned int*)(GP), \
    (__attribute__((address_space(3))) unsigned int*)(&SMEM[LIDX]), 16, 0, 0)

#define ISSUE_PROJ(BUFO, KT) do{ \
    GLL(Aab + aoff0 + (KT), (BUFO) + lb0); \
    GLL(Aab + aoff1 + (KT), (BUFO) + lb1); \
    GLL(Bhb + aoff0 + (KT), (BUFO) + 4096 + lb0); \
    GLL(Bhb + aoff1 + (KT), (BUFO) + 4096 + lb1); \
  }while(0)

  const int csw = (((4*(c & 1) + g) ^ ((c >> 1) & 7)) << 3);

  ISSUE_PROJ(0, 0);
  int cur = 0;
  for (int kt = 0; kt < DM; kt += 32){
    __syncthreads();                       // drains vmcnt -> buf[cur] ready
    if (kt + 32 < DM) ISSUE_PROJ((cur ^ 1)*8192, kt + 32);

    const ush* As  = SMEM + cur*8192;
    const ush* Bhs = As + 4096;

    bf8_t a_h[4];
    #pragma unroll
    for (int fm = 0; fm < 4; ++fm)
      a_h[fm] = *(const bf8_t*)&As[(32*wr + 8*fm + (c>>1))*64 + csw];
    __builtin_amdgcn_s_setprio(1);
    #pragma unroll
    for (int fn = 0; fn < 4; ++fn){
      bf8_t b_h = *(const bf8_t*)&Bhs[(32*wc + 8*fn + (c>>1))*64 + csw];
      #pragma unroll
      for (int fm = 0; fm < 4; ++fm)
        acc[fm][fn] = MFMA16(a_h[fm], b_h, acc[fm][fn]);
    }
    __builtin_amdgcn_s_setprio(0);
    cur ^= 1;
  }
#undef ISSUE_PROJ
#undef GLL

  if (z == 0){
    #pragma unroll
    for (int fm = 0; fm < 4; ++fm){
      #pragma unroll
      for (int fn = 0; fn < 4; ++fn){
        const int col = n0 + 64*wc + 16*fn + c;
        const float bb = bq[col];
        const int row0 = m0 + 64*wr + 16*fm + 4*g;
        const int hd = col >> 6, d = col & 63;
        #pragma unroll
        for (int r = 0; r < 4; ++r){
          const int row = row0 + r;
          const int b = row >> 10, s = row & 1023;
          Qi[((size_t)(b*NH + hd)*SS + s)*DKH + d] = pkhl(acc[fm][fn][r] + bb);
        }
      }
    }
  } else if (z == 1){
    #pragma unroll
    for (int fm = 0; fm < 4; ++fm){
      #pragma unroll
      for (int fn = 0; fn < 4; ++fn){
        const int col = n0 + 64*wc + 16*fn + c;
        const float bb = bk[col];
        const int row0 = m0 + 64*wr + 16*fm + 4*g;
        const int hd = col >> 6, d = col & 63;
        #pragma unroll
        for (int r = 0; r < 4; ++r){
          const int row = row0 + r;
          const int b = row >> 10, s = row & 1023;
          Kb[((size_t)(b*NH + hd)*SS + s)*DKH + d] = f2bf(acc[fm][fn][r] + bb);
        }
      }
    }
  } else {
    // V: transpose wave's 64(s) x 64(d) sub-tile through LDS -> coalesced (d,s)
    __syncthreads();                      // all waves done reading staging LDS
    ush* Vep = SMEM + w*4224;             // 64 rows(d) x 66 cols(s)
    #pragma unroll
    for (int fm = 0; fm < 4; ++fm){
      #pragma unroll
      for (int fn = 0; fn < 4; ++fn){
        const float bb = bv[n0 + 64*wc + 16*fn + c];
        #pragma unroll
        for (int r = 0; r < 4; ++r)
          Vep[(16*fn + c)*66 + 16*fm + 4*g + r] = f2bf(acc[fm][fn][r] + bb);
      }
    }
    const int b = m0 >> 10;
    const int s0 = (m0 & 1023) + 64*wr;
    const int hd = (n0 >> 6) + wc;
    const size_t vbase = ((size_t)(b*NH + hd))*DKH*SS;
    #pragma unroll
    for (int it = 0; it < 8; ++it){
      const int dr = 8*it + (lane >> 3);
      const int sc = (lane & 7)*8;
      uint4 vv = *(const uint4*)&Vep[dr*66 + sc];
      *(uint4*)&Vt[vbase + (size_t)dr*SS + s0 + sc] = vv;
    }
  }
}

// ---- output projection: C = A(bf16) @ Wo^T + bo, 128x64 tile, paired-row LDS
__global__ __launch_bounds__(256) void gemm_out(
    const ush* __restrict__ Abf, const ush* __restrict__ Bth,
    const float* __restrict__ bias, float* __restrict__ outf)
{
  __shared__ ush As[4096], Bs[2048];

  const int fid = blockIdx.x;
  const int glob = (fid & 7)*64 + (fid >> 3);
  const int m0 = (glob >> 4)*128, n0 = (glob & 15)*64;

  const int tid = threadIdx.x;
  const int lane = tid & 63, w = tid >> 6;
  const int c = lane & 15, g = lane >> 4;
  const int wr = w >> 1, wc = w & 1;

  f32x4 acc[4][2];
  #pragma unroll
  for (int i = 0; i < 4; ++i){ acc[i][0] = (f32x4){0,0,0,0}; acc[i][1] = (f32x4){0,0,0,0}; }

  const int prow = tid >> 3, ci = tid & 7;
  const int lr   = 2*prow + (ci >> 2);
  const int koff = (ci & 3) << 3;
  const int ws0  = prow*64 + ((ci ^ (prow & 7)) << 3);
  const int ws1  = ws0 + 32*64;
  const int csw  = (((4*(c & 1) + g) ^ ((c >> 1) & 7)) << 3);

  uint4 ar0, ar1, brr;
  #define ISSUE_OUT(KT) do{ \
    ar0 = *(const uint4*)(Abf + (size_t)(m0 + lr)*DM + (KT) + koff); \
    ar1 = *(const uint4*)(Abf + (size_t)(m0 + lr + 64)*DM + (KT) + koff); \
    brr = *(const uint4*)(Bth + (size_t)(n0 + lr)*DM + (KT) + koff); \
  }while(0)

  ISSUE_OUT(0);
  for (int kt = 0; kt < DM; kt += 32){
    *(uint4*)&As[ws0] = ar0;
    *(uint4*)&As[ws1] = ar1;
    if (lr < 64) *(uint4*)&Bs[ws0] = brr;
    __syncthreads();
    if (kt + 32 < DM) ISSUE_OUT(kt + 32);

    bf8_t a_h[4];
    #pragma unroll
    for (int fm = 0; fm < 4; ++fm)
      a_h[fm] = *(const bf8_t*)&As[(32*wr + 8*fm + (c>>1))*64 + csw];
    #pragma unroll
    for (int fn = 0; fn < 2; ++fn){
      bf8_t b_h = *(const bf8_t*)&Bs[(16*wc + 8*fn + (c>>1))*64 + csw];
      #pragma unroll
      for (int fm = 0; fm < 4; ++fm)
        acc[fm][fn] = MFMA16(a_h[fm], b_h, acc[fm][fn]);
    }
    __syncthreads();
  }
  #undef ISSUE_OUT

  #pragma unroll
  for (int fm = 0; fm < 4; ++fm){
    #pragma unroll
    for (int fn = 0; fn < 2; ++fn){
      const int col = n0 + 32*wc + 16*fn + c;
      const float bb = bias[col];
      const int row0 = m0 + 64*wr + 16*fm + 4*g;
      #pragma unroll
      for (int r = 0; r < 4; ++r)
        outf[(size_t)(row0 + r)*DM + col] = acc[fm][fn][r] + bb;
    }
  }
}

// ---- Stats pass: QBLK=128 (512 thr), KVBLK=128 (8 iters), 1-term QK (Qh),
// plain-bf16 K staging, prefetch; fused time-MLP.
__global__ __launch_bounds__(512) void attn_stats_mfma(
    const uint32* __restrict__ Qi, const ush* __restrict__ Kb,
    float* __restrict__ stats, unsigned int* __restrict__ cnt,
    const float* __restrict__ Wt1, const float* __restrict__ bt1,
    const float* __restrict__ Wt2, const float* __restrict__ bt2,
    float* __restrict__ tws)
{
  __shared__ ush Khs[128*64];                     // 16 KB
  __shared__ float red[8][3];
  const int tid = threadIdx.x, lane = tid & 63, w = tid >> 6;   // w 0..7
  const int c = lane & 15, g = lane >> 4;
  const int fid = blockIdx.x;
  const int glob = (fid & 7)*64 + (fid >> 3);     // 512 blocks, XCD-chunked
  const int bh = glob >> 3, q0 = (glob & 7)*128;

  bf8_t qh[2];
  {
    const size_t qoff = ((size_t)bh*SS + q0 + 16*w + c)*DKH + 8*g;
    uint4 u0 = *(const uint4*)(Qi + qoff);
    uint4 u1 = *(const uint4*)(Qi + qoff + 4);
    uint4 u2 = *(const uint4*)(Qi + qoff + 32);
    uint4 u3 = *(const uint4*)(Qi + qoff + 36);
    U4B8 t;
    t.u = (uint4){prmh(u0.y,u0.x), prmh(u0.w,u0.z), prmh(u1.y,u1.x), prmh(u1.w,u1.z)}; qh[0] = t.b;
    t.u = (uint4){prmh(u2.y,u2.x), prmh(u2.w,u2.z), prmh(u3.y,u3.x), prmh(u3.w,u3.z)}; qh[1] = t.b;
  }

  float ssum = 0.f, rmax = -1e30f, lsum = 0.f, l2sum = 0.f;
  const int rrK = tid >> 2, chK = (tid & 3)*2;    // 128 rows x (2 of 8 chunks)

  uint4 k0, k1;
  #define ISSUE_ST(KC) do{ \
    const ush* kp = Kb + ((size_t)bh*SS + (KC)*128 + rrK)*DKH + chK*8; \
    k0 = *(const uint4*)(kp); \
    k1 = *(const uint4*)(kp + 8); \
  }while(0)

  ISSUE_ST(0);
  for (int kc = 0; kc < 8; ++kc){
    *(uint4*)&Khs[rrK*64 + (((chK + 0) ^ (rrK & 7)) << 3)] = k0;
    *(uint4*)&Khs[rrK*64 + (((chK + 1) ^ (rrK & 7)) << 3)] = k1;
    __syncthreads();
    if (kc < 7) ISSUE_ST(kc + 1);

    f32x4 sa[8];
    #pragma unroll
    for (int fn = 0; fn < 8; ++fn) sa[fn] = (f32x4){0.f,0.f,0.f,0.f};
    __builtin_amdgcn_s_setprio(1);
    #pragma unroll
    for (int fn = 0; fn < 8; ++fn){
      #pragma unroll
      for (int ds = 0; ds < 2; ++ds){
        bf8_t ah = *(const bf8_t*)&Khs[(16*fn + c)*64 + (((g + 4*ds) ^ (c & 7)) << 3)];
        sa[fn] = MFMA16(ah, qh[ds], sa[fn]);      // 1-term: Kh . Qh
      }
    }
    __builtin_amdgcn_s_setprio(0);
    #pragma unroll
    for (int fn = 0; fn < 8; ++fn){
      #pragma unroll
      for (int r = 0; r < 4; ++r){
        float s = sa[fn][r] * 0.125f;
        ssum += s;
        rmax = fmaxf(rmax, s);
        float e = exp2f(s * 0.7213475204f);       // exp(s/2); |s|<50 fp32-safe
        lsum += e;
        l2sum = fmaf(e, e, l2sum);
      }
    }
    __syncthreads();
  }
  #undef ISSUE_ST

  rmax  = fmaxf(rmax, __shfl_xor(rmax, 16, 64));
  rmax  = fmaxf(rmax, __shfl_xor(rmax, 32, 64));
  lsum  += __shfl_xor(lsum, 16, 64);   lsum  += __shfl_xor(lsum, 32, 64);
  l2sum += __shfl_xor(l2sum, 16, 64);  l2sum += __shfl_xor(l2sum, 32, 64);
  float varc = (l2sum/(lsum*lsum) - (1.0f/1024.f)) * (1.0f/1023.f);
  float a0 = ssum, a1 = rmax * 0.25f, a2 = varc * 0.25f;
  #pragma unroll
  for (int off = 1; off < 64; off <<= 1){
    a0 += __shfl_xor(a0, off, 64);
    a1 += __shfl_xor(a1, off, 64);
    a2 += __shfl_xor(a2, off, 64);
  }
  if (lane == 0){ red[w][0] = a0; red[w][1] = a1; red[w][2] = a2; }
  __syncthreads();
  if (tid == 0){
    float r0 = 0.f, r1 = 0.f, r2 = 0.f;
    #pragma unroll
    for (int i = 0; i < 8; ++i){ r0 += red[i][0]; r1 += red[i][1]; r2 += red[i][2]; }
    atomicAdd(&stats[bh*4+0], r0);
    atomicAdd(&stats[bh*4+1], r1);
    atomicAdd(&stats[bh*4+2], r2);
    __threadfence();
    if (atomicAdd(&cnt[bh], 1u) == 7u){        // 8 q-blocks per bh
      float v0 = atomicAdd(&stats[bh*4+0], 0.f);
      float v1 = atomicAdd(&stats[bh*4+1], 0.f);
      float v2 = atomicAdd(&stats[bh*4+2], 0.f);
      float mean = fminf(fmaxf(v0 * (1.f/(1024.f*1024.f)), -10.f), 10.f);
      float mx   = fminf(fmaxf(v1 * (1.f/1024.f), -10.f), 10.f);
      float ent  = fminf(fmaxf(v2 * (1.f/1024.f),   0.f),  1.f);
      float raw = bt2[0];
      #pragma unroll
      for (int j = 0; j < 16; ++j){
        float h = tanhf(mean*Wt1[j] + mx*Wt1[16+j] + ent*Wt1[32+j] + bt1[j]);
        raw += h * Wt2[j];
      }
      float sig = 1.f / (1.f + expf(-raw));
      float t = 0.01f + sig * 1.99f;
      t = fminf(fminf(fmaxf(t, 0.01f), 2.0f), 0.85f);
      tws[bh] = t;
    }
  }
}

// ---- Flash pass: QBLK=128 (512 thr), KVBLK=128 (8 iters), swapped QK^T
// 2-term, plain-bf16 K, exp2, defer-max, swizzled LDS, prefetch. LDS = 64 KB.
__global__ __launch_bounds__(512) void attn_flash_mfma(
    const uint32* __restrict__ Qi, const ush* __restrict__ Kb,
    const ush* __restrict__ Vt, const float* __restrict__ tws,
    ush* __restrict__ aout)
{
  __shared__ ush Khs[128*64], Vts[64*128], Ps[128*128];   // 16+16+32 KB
  const int tid = threadIdx.x, lane = tid & 63, w = tid >> 6;   // w 0..7
  const int c = lane & 15, g = lane >> 4;
  const int fid = blockIdx.x;
  const int glob = (fid & 7)*64 + (fid >> 3);     // 512 blocks, XCD-chunked
  const int bh = glob >> 3, q0 = (glob & 7)*128;
  const float tsc2 = (0.5f / tws[bh]) * 1.44269504f;   // exp2 domain

  bf8_t qh[2], ql[2];
  {
    const size_t qoff = ((size_t)bh*SS + q0 + 16*w + c)*DKH + 8*g;
    uint4 u0 = *(const uint4*)(Qi + qoff);
    uint4 u1 = *(const uint4*)(Qi + qoff + 4);
    uint4 u2 = *(const uint4*)(Qi + qoff + 32);
    uint4 u3 = *(const uint4*)(Qi + qoff + 36);
    U4B8 t;
    t.u = (uint4){prmh(u0.y,u0.x), prmh(u0.w,u0.z), prmh(u1.y,u1.x), prmh(u1.w,u1.z)}; qh[0] = t.b;
    t.u = (uint4){prml(u0.y,u0.x), prml(u0.w,u0.z), prml(u1.y,u1.x), prml(u1.w,u1.z)}; ql[0] = t.b;
    t.u = (uint4){prmh(u2.y,u2.x), prmh(u2.w,u2.z), prmh(u3.y,u3.x), prmh(u3.w,u3.z)}; qh[1] = t.b;
    t.u = (uint4){prml(u2.y,u2.x), prml(u2.w,u2.z), prml(u3.y,u3.x), prml(u3.w,u3.z)}; ql[1] = t.b;
  }

  f32x4 o[4];
  #pragma unroll
  for (int i = 0; i < 4; ++i) o[i] = (f32x4){0.f,0.f,0.f,0.f};
  float m = -INFINITY, lpart = 0.f;

  const int rrK = tid >> 2, chK = (tid & 3)*2;    // K: 128 rows x 2 of 8 chunks
  const int rrV = tid >> 3, chV = (tid & 7)*2;    // V: 64 rows x 2 of 16 chunks

  uint4 k0, k1, v0, v1;
  #define ISSUE_FL(KC) do{ \
    const ush* kp = Kb + ((size_t)bh*SS + (KC)*128 + rrK)*DKH + chK*8; \
    k0 = *(const uint4*)(kp); \
    k1 = *(const uint4*)(kp + 8); \
    const ush* vp = Vt + ((size_t)bh*DKH + rrV)*SS + (KC)*128 + chV*8; \
    v0 = *(const uint4*)(vp); \
    v1 = *(const uint4*)(vp + 8); \
  }while(0)

  ISSUE_FL(0);
  for (int kc = 0; kc < 8; ++kc){
    *(uint4*)&Khs[rrK*64  + (((chK + 0) ^ (rrK & 7)) << 3)] = k0;
    *(uint4*)&Khs[rrK*64  + (((chK + 1) ^ (rrK & 7)) << 3)] = k1;
    *(uint4*)&Vts[rrV*128 + (((chV + 0) ^ (rrV & 7)) << 3)] = v0;
    *(uint4*)&Vts[rrV*128 + (((chV + 1) ^ (rrV & 7)) << 3)] = v1;
    __syncthreads();
    if (kc < 7) ISSUE_FL(kc + 1);

    f32x4 sa[8];
    #pragma unroll
    for (int fn = 0; fn < 8; ++fn) sa[fn] = (f32x4){0.f,0.f,0.f,0.f};
    __builtin_amdgcn_s_setprio(1);
    #pragma unroll
    for (int fn = 0; fn < 8; ++fn){
      #pragma unroll
      for (int ds = 0; ds < 2; ++ds){
        bf8_t ah = *(const bf8_t*)&Khs[(16*fn + c)*64 + (((g + 4*ds) ^ (c & 7)) << 3)];
        sa[fn] = MFMA16(ah, qh[ds], sa[fn]);   // 2-term: Kh . (Qh + Ql)
        sa[fn] = MFMA16(ah, ql[ds], sa[fn]);
      }
    }
    __builtin_amdgcn_s_setprio(0);

    // lane-local max over own 32 kv; shuffles only in the rare rescale path
    float pmaxr = -1e30f;
    #pragma unroll
    for (int fn = 0; fn < 8; ++fn)
      #pragma unroll
      for (int r = 0; r < 4; ++r) pmaxr = fmaxf(pmaxr, sa[fn][r]);

    if (!__all(pmaxr * tsc2 <= m + 30.f)){     // fires ~once (kc=0)
      pmaxr = fmaxf(pmaxr, __shfl_xor(pmaxr, 16, 64));
      pmaxr = fmaxf(pmaxr, __shfl_xor(pmaxr, 32, 64));
      float pmax = pmaxr * tsc2;
      float mn = fmaxf(m, pmax);
      float sc = exp2f(m - mn);
      m = mn;
      lpart *= sc;
      #pragma unroll
      for (int r = 0; r < 4; ++r){
        float so = __shfl(sc, 4*g + r, 16);    // sc of q-row 4g+r (c'=4g+r)
        #pragma unroll
        for (int fn = 0; fn < 4; ++fn) o[fn][r] *= so;
      }
    }

    const float mneg = -m;
    #pragma unroll
    for (int fn = 0; fn < 8; ++fn){
      float e0 = exp2f(fmaf(sa[fn][0], tsc2, mneg));
      float e1 = exp2f(fmaf(sa[fn][1], tsc2, mneg));
      float e2 = exp2f(fmaf(sa[fn][2], tsc2, mneg));
      float e3 = exp2f(fmaf(sa[fn][3], tsc2, mneg));
      lpart += (e0 + e1) + (e2 + e3);
      uint2 pk;
      pk.x = pk2(e0, e1);
      pk.y = pk2(e2, e3);
      const int q4 = 4*fn + g;                 // 4-ush kv chunk, 0..31
      const int addr = (16*w + c)*128 + ((((q4 >> 1) ^ (c & 7)) << 3)) + (q4 & 1)*4;
      *(uint2*)&Ps[addr] = pk;
    }

    __builtin_amdgcn_s_setprio(1);
    #pragma unroll
    for (int kvs = 0; kvs < 4; ++kvs){
      bf8_t pa = *(const bf8_t*)&Ps[(16*w + c)*128 + (((g + 4*kvs) ^ (c & 7)) << 3)];
      #pragma unroll
      for (int fn = 0; fn < 4; ++fn){
        bf8_t vb = *(const bf8_t*)&Vts[(16*fn + c)*128 + (((g + 4*kvs) ^ (c & 7)) << 3)];
        o[fn] = MFMA16(pa, vb, o[fn]);
      }
    }
    __builtin_amdgcn_s_setprio(0);
    __syncthreads();
  }
  #undef ISSUE_FL

  lpart += __shfl_xor(lpart, 16, 64);
  lpart += __shfl_xor(lpart, 32, 64);
  const int b = bh >> 4, hd = bh & 15;
  #pragma unroll
  for (int r = 0; r < 4; ++r){
    float linv = 1.f / __shfl(lpart, 4*g + r, 16);   // l of q-row 4g+r
    const int q = q0 + 16*w + 4*g + r;
    #pragma unroll
    for (int fn = 0; fn < 4; ++fn)
      aout[((size_t)(b*SS + q))*DM + hd*DKH + 16*fn + c] = f2bf(o[fn][r] * linv);
  }
}

extern "C" void kernel_launch(void* const* d_in, const int* in_sizes, int n_in,
                              void* d_out, int out_size, void* d_ws, size_t ws_size,
                              hipStream_t stream)
{
  const float* query = (const float*)d_in[0];
  const float* key   = (const float*)d_in[1];
  const float* value = (const float*)d_in[2];
  const float* Wq = (const float*)d_in[3];
  const float* bq = (const float*)d_in[4];
  const float* Wk = (const float*)d_in[5];
  const float* bk = (const float*)d_in[6];
  const float* Wv = (const float*)d_in[7];
  const float* bv = (const float*)d_in[8];
  const float* Wo = (const float*)d_in[9];
  const float* bo = (const float*)d_in[10];
  const float* Wt1 = (const float*)d_in[11];
  const float* bt1 = (const float*)d_in[12];
  const float* Wt2 = (const float*)d_in[13];
  const float* bt2 = (const float*)d_in[14];

  const size_t E = (size_t)NB*SS*DM;       // 4,194,304
  const size_t WE = (size_t)DM*DM;

  uint32* Qi  = (uint32*)d_ws;             // E uint32 (hi|lo interleaved)
  ush* Kbb = (ush*)(Qi + E);               // E ush (plain bf16)
  ush* Vtb = Kbb + E;                      // E ush (b*16+h, dk, s)
  ush* Aob = Vtb + E;                      // E ush  -- also aliased as xqb
  ush* xqb = Aob;                          // alias: consumed before Aob written
  ush* xkb = Aob + E;
  ush* xvb = xkb + E;
  ush* Wqh = xvb + E;
  ush* Wkh = Wqh + WE;
  ush* Wvh = Wkh + WE;
  ush* Woh = Wvh + WE;
  float* stats = (float*)(Woh + WE);                  // 256 floats
  unsigned int* cnt = (unsigned int*)(stats + 4*NBH); // 64 uints
  float* tws   = (float*)(cnt + NBH);

  hipMemsetAsync(stats, 0, (4*NBH + NBH)*sizeof(float), stream);

  xconv<<<dim3(2048, 3), 256, 0, stream>>>(query, key, value, xqb, xkb, xvb);

  dim3 wb(32, 8), wg(32, 32, 4);
  wconv4<<<wg, wb, 0, stream>>>(Wq, Wk, Wv, Wo, Wqh, Wkh, Wvh, Woh);

  proj_qkv<<<768, 256, 0, stream>>>(xqb, xkb, xvb,
      Wqh, Wkh, Wvh, bq, bk, bv, Qi, Kbb, Vtb);

  attn_stats_mfma<<<512, 512, 0, stream>>>(Qi, Kbb, stats, cnt,
      Wt1, bt1, Wt2, bt2, tws);
  attn_flash_mfma<<<512, 512, 0, stream>>>(Qi, Kbb, Vtb, tws, Aob);

  gemm_out<<<512, 256, 0, stream>>>(Aob, Woh, bo, (float*)d_out);
}

// Round 16
// 152.174 us; speedup vs baseline: 1.0838x; 1.0838x over previous
//
#include <hip/hip_runtime.h>
#include <hip/hip_bf16.h>
#include <math.h>

#define SS   1024
#define DM   1024
#define NH   16
#define DKH  64
#define NB   4
#define NBH  64

typedef unsigned short ush;
typedef unsigned int uint32;
typedef __attribute__((ext_vector_type(8))) short bf8_t;   // 8 bf16 = 4 VGPR
typedef __attribute__((ext_vector_type(4))) float f32x4;
#define MFMA16(a,b,c) __builtin_amdgcn_mfma_f32_16x16x32_bf16((a),(b),(c),0,0,0)

__device__ __forceinline__ ush f2bf(float x){ return __bfloat16_as_ushort(__float2bfloat16(x)); }
__device__ __forceinline__ float bf2f(ush h){ return __bfloat162float(__ushort_as_bfloat16(h)); }
__device__ __forceinline__ uint32 pk2(float a, float b){
  return (uint32)f2bf(a) | ((uint32)f2bf(b) << 16);
}
// pack value as (lo16<<16)|hi16
__device__ __forceinline__ uint32 pkhl(float v){
  ush h = f2bf(v);
  return (uint32)h | ((uint32)f2bf(v - bf2f(h)) << 16);
}
// extract hi/lo bf16 pairs from two interleaved uints (ulo = smaller d)
__device__ __forceinline__ uint32 prmh(uint32 uhi, uint32 ulo){
  return __builtin_amdgcn_perm(uhi, ulo, 0x05040100u);
}
__device__ __forceinline__ uint32 prml(uint32 uhi, uint32 ulo){
  return __builtin_amdgcn_perm(uhi, ulo, 0x07060302u);
}
// [rows][64]-ush tile, XOR swizzle on 16B chunks
__device__ __forceinline__ int swz8(int row, int chunk){
  return row*64 + (((chunk) ^ (row & 7)) << 3);
}
union U4B8 { uint4 u; bf8_t b; };

// ---- x fp32 -> bf16 (hi only)
__global__ __launch_bounds__(256) void xconv(
    const float* __restrict__ q, const float* __restrict__ k, const float* __restrict__ v,
    ush* __restrict__ xq, ush* __restrict__ xk, ush* __restrict__ xv)
{
  const float* src = (blockIdx.y==0)?q:(blockIdx.y==1)?k:v;
  ush* dst = (blockIdx.y==0)?xq:(blockIdx.y==1)?xk:xv;
  const size_t i = ((size_t)blockIdx.x*256 + threadIdx.x)*8;
  float4 a = *(const float4*)&src[i];
  float4 b = *(const float4*)&src[i+4];
  uint4 o;
  o.x = pk2(a.x, a.y); o.y = pk2(a.z, a.w);
  o.z = pk2(b.x, b.y); o.w = pk2(b.z, b.w);
  *(uint4*)&dst[i] = o;
}

// ---- weight convert: W (K x N) fp32 -> Wt (N x K) bf16 hi only
__global__ void wconv4(const float* __restrict__ W0, const float* __restrict__ W1,
                       const float* __restrict__ W2, const float* __restrict__ W3,
                       ush* __restrict__ H0, ush* __restrict__ H1,
                       ush* __restrict__ H2, ush* __restrict__ H3)
{
  __shared__ float T[32][33];
  const int tx = threadIdx.x, ty = threadIdx.y;    // (32,8)
  const int z = blockIdx.z;
  const float* W = (z==0)?W0:(z==1)?W1:(z==2)?W2:W3;
  ush* H = (z==0)?H0:(z==1)?H1:(z==2)?H2:H3;
  const int k0 = blockIdx.y*32, n0 = blockIdx.x*32;
  #pragma unroll
  for (int i = 0; i < 4; ++i){
    int r = ty + 8*i;
    T[r][tx] = W[(size_t)(k0 + r)*DM + n0 + tx];
  }
  __syncthreads();
  #pragma unroll
  for (int i = 0; i < 4; ++i){
    int r = ty + 8*i;              // n-local
    H[(size_t)(n0 + r)*DM + k0 + tx] = f2bf(T[tx][r]);
  }
}

// ---- fused Q/K/V projection: BK=32, 1-term (W hi), double-buffered LDS via
// global_load_lds width-16 with pre-swizzled per-lane SOURCE addresses.
__global__ __launch_bounds__(256) void proj_qkv(
    const ush* __restrict__ xq, const ush* __restrict__ xk, const ush* __restrict__ xv,
    const ush* __restrict__ Wqh, const ush* __restrict__ Wkh, const ush* __restrict__ Wvh,
    const float* __restrict__ bq, const float* __restrict__ bk,
    const float* __restrict__ bv,
    uint32* __restrict__ Qi, ush* __restrict__ Kb, ush* __restrict__ Vt)
{
  // staging: 2 buffers x (As 4096 | Bhs 4096) = 32 KB; V-epilogue 4*4224 ush
  __shared__ ush SMEM[16896];

  const int fid = blockIdx.x;
  const int glob = (fid & 7)*96 + (fid >> 3);  // XCD-contiguous chunks of 96
  const int z = glob >> 8, rem = glob & 255;
  const int m0 = (rem >> 3) * 128, n0 = (rem & 7) * 128;

  const ush* A  = (z==0) ? xq  : (z==1) ? xk  : xv;
  const ush* Bh = (z==0) ? Wqh : (z==1) ? Wkh : Wvh;

  const int tid = threadIdx.x;
  const int lane = tid & 63, w = tid >> 6;
  const int c = lane & 15, g = lane >> 4;
  const int wr = w >> 1, wc = w & 1;

  f32x4 acc[4][4];
  #pragma unroll
  for (int i = 0; i < 4; ++i)
    #pragma unroll
    for (int j = 0; j < 4; ++j) acc[i][j] = (f32x4){0.f,0.f,0.f,0.f};

  const int prow0 = w*16 + (lane >> 3), prow1 = prow0 + 8;
  const int jj = lane & 7;
  const int sg0 = jj ^ (prow0 & 7), sg1 = jj ^ (prow1 & 7);
  const size_t aoff0 = (size_t)(2*prow0 + (sg0 >> 2))*DM + (sg0 & 3)*8;
  const size_t aoff1 = (size_t)(2*prow1 + (sg1 >> 2))*DM + (sg1 & 3)*8;
  const ush* Aab = A  + (size_t)m0*DM;
  const ush* Bhb = Bh + (size_t)n0*DM;
  const int lb0 = w*1024, lb1 = w*1024 + 512;   // wave-uniform LDS bases (ush)

#define GLL(GP, LIDX) __builtin_amdgcn_global_load_lds( \
    (const __attribute__((address_space(1))) unsigned int*)(GP), \
    (__attribute__((address_space(3))) unsigned int*)(&SMEM[LIDX]), 16, 0, 0)

#define ISSUE_PROJ(BUFO, KT) do{ \
    GLL(Aab + aoff0 + (KT), (BUFO) + lb0); \
    GLL(Aab + aoff1 + (KT), (BUFO) + lb1); \
    GLL(Bhb + aoff0 + (KT), (BUFO) + 4096 + lb0); \
    GLL(Bhb + aoff1 + (KT), (BUFO) + 4096 + lb1); \
  }while(0)

  const int csw = (((4*(c & 1) + g) ^ ((c >> 1) & 7)) << 3);

  ISSUE_PROJ(0, 0);
  int cur = 0;
  for (int kt = 0; kt < DM; kt += 32){
    __syncthreads();                       // drains vmcnt -> buf[cur] ready
    if (kt + 32 < DM) ISSUE_PROJ((cur ^ 1)*8192, kt + 32);

    const ush* As  = SMEM + cur*8192;
    const ush* Bhs = As + 4096;

    bf8_t a_h[4];
    #pragma unroll
    for (int fm = 0; fm < 4; ++fm)
      a_h[fm] = *(const bf8_t*)&As[(32*wr + 8*fm + (c>>1))*64 + csw];
    __builtin_amdgcn_s_setprio(1);
    #pragma unroll
    for (int fn = 0; fn < 4; ++fn){
      bf8_t b_h = *(const bf8_t*)&Bhs[(32*wc + 8*fn + (c>>1))*64 + csw];
      #pragma unroll
      for (int fm = 0; fm < 4; ++fm)
        acc[fm][fn] = MFMA16(a_h[fm], b_h, acc[fm][fn]);
    }
    __builtin_amdgcn_s_setprio(0);
    cur ^= 1;
  }
#undef ISSUE_PROJ
#undef GLL

  if (z == 0){
    #pragma unroll
    for (int fm = 0; fm < 4; ++fm){
      #pragma unroll
      for (int fn = 0; fn < 4; ++fn){
        const int col = n0 + 64*wc + 16*fn + c;
        const float bb = bq[col];
        const int row0 = m0 + 64*wr + 16*fm + 4*g;
        const int hd = col >> 6, d = col & 63;
        #pragma unroll
        for (int r = 0; r < 4; ++r){
          const int row = row0 + r;
          const int b = row >> 10, s = row & 1023;
          Qi[((size_t)(b*NH + hd)*SS + s)*DKH + d] = pkhl(acc[fm][fn][r] + bb);
        }
      }
    }
  } else if (z == 1){
    #pragma unroll
    for (int fm = 0; fm < 4; ++fm){
      #pragma unroll
      for (int fn = 0; fn < 4; ++fn){
        const int col = n0 + 64*wc + 16*fn + c;
        const float bb = bk[col];
        const int row0 = m0 + 64*wr + 16*fm + 4*g;
        const int hd = col >> 6, d = col & 63;
        #pragma unroll
        for (int r = 0; r < 4; ++r){
          const int row = row0 + r;
          const int b = row >> 10, s = row & 1023;
          Kb[((size_t)(b*NH + hd)*SS + s)*DKH + d] = f2bf(acc[fm][fn][r] + bb);
        }
      }
    }
  } else {
    // V: transpose wave's 64(s) x 64(d) sub-tile through LDS -> coalesced (d,s)
    __syncthreads();                      // all waves done reading staging LDS
    ush* Vep = SMEM + w*4224;             // 64 rows(d) x 66 cols(s)
    #pragma unroll
    for (int fm = 0; fm < 4; ++fm){
      #pragma unroll
      for (int fn = 0; fn < 4; ++fn){
        const float bb = bv[n0 + 64*wc + 16*fn + c];
        #pragma unroll
        for (int r = 0; r < 4; ++r)
          Vep[(16*fn + c)*66 + 16*fm + 4*g + r] = f2bf(acc[fm][fn][r] + bb);
      }
    }
    const int b = m0 >> 10;
    const int s0 = (m0 & 1023) + 64*wr;
    const int hd = (n0 >> 6) + wc;
    const size_t vbase = ((size_t)(b*NH + hd))*DKH*SS;
    #pragma unroll
    for (int it = 0; it < 8; ++it){
      const int dr = 8*it + (lane >> 3);
      const int sc = (lane & 7)*8;
      uint4 vv = *(const uint4*)&Vep[dr*66 + sc];
      *(uint4*)&Vt[vbase + (size_t)dr*SS + s0 + sc] = vv;
    }
  }
}

// ---- output projection: C = A(bf16) @ Wo^T + bo, 128x64 tile, paired-row LDS
__global__ __launch_bounds__(256) void gemm_out(
    const ush* __restrict__ Abf, const ush* __restrict__ Bth,
    const float* __restrict__ bias, float* __restrict__ outf)
{
  __shared__ ush As[4096], Bs[2048];

  const int fid = blockIdx.x;
  const int glob = (fid & 7)*64 + (fid >> 3);
  const int m0 = (glob >> 4)*128, n0 = (glob & 15)*64;

  const int tid = threadIdx.x;
  const int lane = tid & 63, w = tid >> 6;
  const int c = lane & 15, g = lane >> 4;
  const int wr = w >> 1, wc = w & 1;

  f32x4 acc[4][2];
  #pragma unroll
  for (int i = 0; i < 4; ++i){ acc[i][0] = (f32x4){0,0,0,0}; acc[i][1] = (f32x4){0,0,0,0}; }

  const int prow = tid >> 3, ci = tid & 7;
  const int lr   = 2*prow + (ci >> 2);
  const int koff = (ci & 3) << 3;
  const int ws0  = prow*64 + ((ci ^ (prow & 7)) << 3);
  const int ws1  = ws0 + 32*64;
  const int csw  = (((4*(c & 1) + g) ^ ((c >> 1) & 7)) << 3);

  uint4 ar0, ar1, brr;
  #define ISSUE_OUT(KT) do{ \
    ar0 = *(const uint4*)(Abf + (size_t)(m0 + lr)*DM + (KT) + koff); \
    ar1 = *(const uint4*)(Abf + (size_t)(m0 + lr + 64)*DM + (KT) + koff); \
    brr = *(const uint4*)(Bth + (size_t)(n0 + lr)*DM + (KT) + koff); \
  }while(0)

  ISSUE_OUT(0);
  for (int kt = 0; kt < DM; kt += 32){
    *(uint4*)&As[ws0] = ar0;
    *(uint4*)&As[ws1] = ar1;
    if (lr < 64) *(uint4*)&Bs[ws0] = brr;
    __syncthreads();
    if (kt + 32 < DM) ISSUE_OUT(kt + 32);

    bf8_t a_h[4];
    #pragma unroll
    for (int fm = 0; fm < 4; ++fm)
      a_h[fm] = *(const bf8_t*)&As[(32*wr + 8*fm + (c>>1))*64 + csw];
    #pragma unroll
    for (int fn = 0; fn < 2; ++fn){
      bf8_t b_h = *(const bf8_t*)&Bs[(16*wc + 8*fn + (c>>1))*64 + csw];
      #pragma unroll
      for (int fm = 0; fm < 4; ++fm)
        acc[fm][fn] = MFMA16(a_h[fm], b_h, acc[fm][fn]);
    }
    __syncthreads();
  }
  #undef ISSUE_OUT

  #pragma unroll
  for (int fm = 0; fm < 4; ++fm){
    #pragma unroll
    for (int fn = 0; fn < 2; ++fn){
      const int col = n0 + 32*wc + 16*fn + c;
      const float bb = bias[col];
      const int row0 = m0 + 64*wr + 16*fm + 4*g;
      #pragma unroll
      for (int r = 0; r < 4; ++r)
        outf[(size_t)(row0 + r)*DM + col] = acc[fm][fn][r] + bb;
    }
  }
}

// ---- Stats pass: QBLK=128 (512 thr, 8 waves), KVBLK=64, 1-term QK (Qh),
// plain-bf16 K staging, prefetch. Atomic partial sums only (no election).
__global__ __launch_bounds__(512) void attn_stats_mfma(
    const uint32* __restrict__ Qi, const ush* __restrict__ Kb,
    float* __restrict__ stats)
{
  __shared__ ush Khs[64*64];
  __shared__ float red[8][3];
  const int tid = threadIdx.x, lane = tid & 63, w = tid >> 6;   // w 0..7
  const int c = lane & 15, g = lane >> 4;
  const int fid = blockIdx.x;
  const int glob = (fid & 7)*64 + (fid >> 3);     // 512 blocks, XCD-chunked
  const int bh = glob >> 3, q0 = (glob & 7)*128;

  bf8_t qh[2];
  {
    const size_t qoff = ((size_t)bh*SS + q0 + 16*w + c)*DKH + 8*g;
    uint4 u0 = *(const uint4*)(Qi + qoff);
    uint4 u1 = *(const uint4*)(Qi + qoff + 4);
    uint4 u2 = *(const uint4*)(Qi + qoff + 32);
    uint4 u3 = *(const uint4*)(Qi + qoff + 36);
    U4B8 t;
    t.u = (uint4){prmh(u0.y,u0.x), prmh(u0.w,u0.z), prmh(u1.y,u1.x), prmh(u1.w,u1.z)}; qh[0] = t.b;
    t.u = (uint4){prmh(u2.y,u2.x), prmh(u2.w,u2.z), prmh(u3.y,u3.x), prmh(u3.w,u3.z)}; qh[1] = t.b;
  }

  float ssum = 0.f, rmax = -1e30f, lsum = 0.f, l2sum = 0.f;
  const int rr0 = tid >> 3, ci = tid & 7;         // 64 rows x 8 chunks

  uint4 k0;
  #define ISSUE_ST(KC) do{ \
    k0 = *(const uint4*)(Kb + ((size_t)bh*SS + (KC)*64 + rr0)*DKH + ci*8); \
  }while(0)

  ISSUE_ST(0);
  for (int kc = 0; kc < 16; ++kc){
    *(uint4*)&Khs[swz8(rr0, ci)] = k0;
    __syncthreads();
    if (kc < 15) ISSUE_ST(kc + 1);

    f32x4 sa[4];
    #pragma unroll
    for (int fn = 0; fn < 4; ++fn) sa[fn] = (f32x4){0.f,0.f,0.f,0.f};
    __builtin_amdgcn_s_setprio(1);
    #pragma unroll
    for (int fn = 0; fn < 4; ++fn){
      #pragma unroll
      for (int ds = 0; ds < 2; ++ds){
        bf8_t ah = *(const bf8_t*)&Khs[swz8(16*fn + c, g + 4*ds)];
        sa[fn] = MFMA16(ah, qh[ds], sa[fn]);      // 1-term: Kh . Qh
      }
    }
    __builtin_amdgcn_s_setprio(0);
    #pragma unroll
    for (int fn = 0; fn < 4; ++fn){
      #pragma unroll
      for (int r = 0; r < 4; ++r){
        float s = sa[fn][r] * 0.125f;
        ssum += s;
        rmax = fmaxf(rmax, s);
        float e = exp2f(s * 0.7213475204f);       // exp(s/2); |s|<50 fp32-safe
        lsum += e;
        l2sum = fmaf(e, e, l2sum);
      }
    }
    __syncthreads();
  }
  #undef ISSUE_ST

  rmax  = fmaxf(rmax, __shfl_xor(rmax, 16, 64));
  rmax  = fmaxf(rmax, __shfl_xor(rmax, 32, 64));
  lsum  += __shfl_xor(lsum, 16, 64);   lsum  += __shfl_xor(lsum, 32, 64);
  l2sum += __shfl_xor(l2sum, 16, 64);  l2sum += __shfl_xor(l2sum, 32, 64);
  float varc = (l2sum/(lsum*lsum) - (1.0f/1024.f)) * (1.0f/1023.f);
  float a0 = ssum, a1 = rmax * 0.25f, a2 = varc * 0.25f;
  #pragma unroll
  for (int off = 1; off < 64; off <<= 1){
    a0 += __shfl_xor(a0, off, 64);
    a1 += __shfl_xor(a1, off, 64);
    a2 += __shfl_xor(a2, off, 64);
  }
  if (lane == 0){ red[w][0] = a0; red[w][1] = a1; red[w][2] = a2; }
  __syncthreads();
  if (tid == 0){
    float r0 = 0.f, r1 = 0.f, r2 = 0.f;
    #pragma unroll
    for (int i = 0; i < 8; ++i){ r0 += red[i][0]; r1 += red[i][1]; r2 += red[i][2]; }
    atomicAdd(&stats[bh*4+0], r0);
    atomicAdd(&stats[bh*4+1], r1);
    atomicAdd(&stats[bh*4+2], r2);
  }
}

// ---- time-predictor MLP (separate kernel: no cross-block protocol)
__global__ void time_mlp(const float* __restrict__ stats,
    const float* __restrict__ Wt1, const float* __restrict__ bt1,
    const float* __restrict__ Wt2, const float* __restrict__ bt2,
    float* __restrict__ tws)
{
  int bh = threadIdx.x;
  if (bh >= NBH) return;
  float mean = fminf(fmaxf(stats[bh*4+0] * (1.f/(1024.f*1024.f)), -10.f), 10.f);
  float mx   = fminf(fmaxf(stats[bh*4+1] * (1.f/1024.f), -10.f), 10.f);
  float ent  = fminf(fmaxf(stats[bh*4+2] * (1.f/1024.f),   0.f),  1.f);
  float raw = bt2[0];
  #pragma unroll
  for (int j = 0; j < 16; ++j){
    float h = tanhf(mean*Wt1[j] + mx*Wt1[16+j] + ent*Wt1[32+j] + bt1[j]);
    raw += h * Wt2[j];
  }
  float sig = 1.f / (1.f + expf(-raw));
  float t = 0.01f + sig * 1.99f;
  t = fminf(fminf(fmaxf(t, 0.01f), 2.0f), 0.85f);
  tws[bh] = t;
}

// ---- Flash pass: QBLK=128 (512 thr), KVBLK=128 (8 iters), swapped QK^T
// 2-term, plain-bf16 K, exp2, defer-max, swizzled LDS, prefetch. LDS = 64 KB.
__global__ __launch_bounds__(512) void attn_flash_mfma(
    const uint32* __restrict__ Qi, const ush* __restrict__ Kb,
    const ush* __restrict__ Vt, const float* __restrict__ tws,
    ush* __restrict__ aout)
{
  __shared__ ush Khs[128*64], Vts[64*128], Ps[128*128];   // 16+16+32 KB
  const int tid = threadIdx.x, lane = tid & 63, w = tid >> 6;   // w 0..7
  const int c = lane & 15, g = lane >> 4;
  const int fid = blockIdx.x;
  const int glob = (fid & 7)*64 + (fid >> 3);     // 512 blocks, XCD-chunked
  const int bh = glob >> 3, q0 = (glob & 7)*128;
  const float tsc2 = (0.5f / tws[bh]) * 1.44269504f;   // exp2 domain

  bf8_t qh[2], ql[2];
  {
    const size_t qoff = ((size_t)bh*SS + q0 + 16*w + c)*DKH + 8*g;
    uint4 u0 = *(const uint4*)(Qi + qoff);
    uint4 u1 = *(const uint4*)(Qi + qoff + 4);
    uint4 u2 = *(const uint4*)(Qi + qoff + 32);
    uint4 u3 = *(const uint4*)(Qi + qoff + 36);
    U4B8 t;
    t.u = (uint4){prmh(u0.y,u0.x), prmh(u0.w,u0.z), prmh(u1.y,u1.x), prmh(u1.w,u1.z)}; qh[0] = t.b;
    t.u = (uint4){prml(u0.y,u0.x), prml(u0.w,u0.z), prml(u1.y,u1.x), prml(u1.w,u1.z)}; ql[0] = t.b;
    t.u = (uint4){prmh(u2.y,u2.x), prmh(u2.w,u2.z), prmh(u3.y,u3.x), prmh(u3.w,u3.z)}; qh[1] = t.b;
    t.u = (uint4){prml(u2.y,u2.x), prml(u2.w,u2.z), prml(u3.y,u3.x), prml(u3.w,u3.z)}; ql[1] = t.b;
  }

  f32x4 o[4];
  #pragma unroll
  for (int i = 0; i < 4; ++i) o[i] = (f32x4){0.f,0.f,0.f,0.f};
  float m = -INFINITY, lpart = 0.f;

  const int rrK = tid >> 2, chK = (tid & 3)*2;    // K: 128 rows x 2 of 8 chunks
  const int rrV = tid >> 3, chV = (tid & 7)*2;    // V: 64 rows x 2 of 16 chunks

  uint4 k0, k1, v0, v1;
  #define ISSUE_FL(KC) do{ \
    const ush* kp = Kb + ((size_t)bh*SS + (KC)*128 + rrK)*DKH + chK*8; \
    k0 = *(const uint4*)(kp); \
    k1 = *(const uint4*)(kp + 8); \
    const ush* vp = Vt + ((size_t)bh*DKH + rrV)*SS + (KC)*128 + chV*8; \
    v0 = *(const uint4*)(vp); \
    v1 = *(const uint4*)(vp + 8); \
  }while(0)

  ISSUE_FL(0);
  for (int kc = 0; kc < 8; ++kc){
    *(uint4*)&Khs[rrK*64  + (((chK + 0) ^ (rrK & 7)) << 3)] = k0;
    *(uint4*)&Khs[rrK*64  + (((chK + 1) ^ (rrK & 7)) << 3)] = k1;
    *(uint4*)&Vts[rrV*128 + (((chV + 0) ^ (rrV & 7)) << 3)] = v0;
    *(uint4*)&Vts[rrV*128 + (((chV + 1) ^ (rrV & 7)) << 3)] = v1;
    __syncthreads();
    if (kc < 7) ISSUE_FL(kc + 1);

    f32x4 sa[8];
    #pragma unroll
    for (int fn = 0; fn < 8; ++fn) sa[fn] = (f32x4){0.f,0.f,0.f,0.f};
    __builtin_amdgcn_s_setprio(1);
    #pragma unroll
    for (int fn = 0; fn < 8; ++fn){
      #pragma unroll
      for (int ds = 0; ds < 2; ++ds){
        bf8_t ah = *(const bf8_t*)&Khs[(16*fn + c)*64 + (((g + 4*ds) ^ (c & 7)) << 3)];
        sa[fn] = MFMA16(ah, qh[ds], sa[fn]);   // 2-term: Kh . (Qh + Ql)
        sa[fn] = MFMA16(ah, ql[ds], sa[fn]);
      }
    }
    __builtin_amdgcn_s_setprio(0);

    // lane-local max over own 32 kv; shuffles only in the rare rescale path
    float pmaxr = -1e30f;
    #pragma unroll
    for (int fn = 0; fn < 8; ++fn)
      #pragma unroll
      for (int r = 0; r < 4; ++r) pmaxr = fmaxf(pmaxr, sa[fn][r]);

    if (!__all(pmaxr * tsc2 <= m + 30.f)){     // fires ~once (kc=0)
      pmaxr = fmaxf(pmaxr, __shfl_xor(pmaxr, 16, 64));
      pmaxr = fmaxf(pmaxr, __shfl_xor(pmaxr, 32, 64));
      float pmax = pmaxr * tsc2;
      float mn = fmaxf(m, pmax);
      float sc = exp2f(m - mn);
      m = mn;
      lpart *= sc;
      #pragma unroll
      for (int r = 0; r < 4; ++r){
        float so = __shfl(sc, 4*g + r, 16);    // sc of q-row 4g+r (c'=4g+r)
        #pragma unroll
        for (int fn = 0; fn < 4; ++fn) o[fn][r] *= so;
      }
    }

    const float mneg = -m;
    #pragma unroll
    for (int fn = 0; fn < 8; ++fn){
      float e0 = exp2f(fmaf(sa[fn][0], tsc2, mneg));
      float e1 = exp2f(fmaf(sa[fn][1], tsc2, mneg));
      float e2 = exp2f(fmaf(sa[fn][2], tsc2, mneg));
      float e3 = exp2f(fmaf(sa[fn][3], tsc2, mneg));
      lpart += (e0 + e1) + (e2 + e3);
      uint2 pk;
      pk.x = pk2(e0, e1);
      pk.y = pk2(e2, e3);
      const int q4 = 4*fn + g;                 // 4-ush kv chunk, 0..31
      const int addr = (16*w + c)*128 + ((((q4 >> 1) ^ (c & 7)) << 3)) + (q4 & 1)*4;
      *(uint2*)&Ps[addr] = pk;
    }

    __builtin_amdgcn_s_setprio(1);
    #pragma unroll
    for (int kvs = 0; kvs < 4; ++kvs){
      bf8_t pa = *(const bf8_t*)&Ps[(16*w + c)*128 + (((g + 4*kvs) ^ (c & 7)) << 3)];
      #pragma unroll
      for (int fn = 0; fn < 4; ++fn){
        bf8_t vb = *(const bf8_t*)&Vts[(16*fn + c)*128 + (((g + 4*kvs) ^ (c & 7)) << 3)];
        o[fn] = MFMA16(pa, vb, o[fn]);
      }
    }
    __builtin_amdgcn_s_setprio(0);
    __syncthreads();
  }
  #undef ISSUE_FL

  lpart += __shfl_xor(lpart, 16, 64);
  lpart += __shfl_xor(lpart, 32, 64);
  const int b = bh >> 4, hd = bh & 15;
  #pragma unroll
  for (int r = 0; r < 4; ++r){
    float linv = 1.f / __shfl(lpart, 4*g + r, 16);   // l of q-row 4g+r
    const int q = q0 + 16*w + 4*g + r;
    #pragma unroll
    for (int fn = 0; fn < 4; ++fn)
      aout[((size_t)(b*SS + q))*DM + hd*DKH + 16*fn + c] = f2bf(o[fn][r] * linv);
  }
}

extern "C" void kernel_launch(void* const* d_in, const int* in_sizes, int n_in,
                              void* d_out, int out_size, void* d_ws, size_t ws_size,
                              hipStream_t stream)
{
  const float* query = (const float*)d_in[0];
  const float* key   = (const float*)d_in[1];
  const float* value = (const float*)d_in[2];
  const float* Wq = (const float*)d_in[3];
  const float* bq = (const float*)d_in[4];
  const float* Wk = (const float*)d_in[5];
  const float* bk = (const float*)d_in[6];
  const float* Wv = (const float*)d_in[7];
  const float* bv = (const float*)d_in[8];
  const float* Wo = (const float*)d_in[9];
  const float* bo = (const float*)d_in[10];
  const float* Wt1 = (const float*)d_in[11];
  const float* bt1 = (const float*)d_in[12];
  const float* Wt2 = (const float*)d_in[13];
  const float* bt2 = (const float*)d_in[14];

  const size_t E = (size_t)NB*SS*DM;       // 4,194,304
  const size_t WE = (size_t)DM*DM;

  uint32* Qi  = (uint32*)d_ws;             // E uint32 (hi|lo interleaved)
  ush* Kbb = (ush*)(Qi + E);               // E ush (plain bf16)
  ush* Vtb = Kbb + E;                      // E ush (b*16+h, dk, s)
  ush* Aob = Vtb + E;                      // E ush  -- also aliased as xqb
  ush* xqb = Aob;                          // alias: consumed before Aob written
  ush* xkb = Aob + E;
  ush* xvb = xkb + E;
  ush* Wqh = xvb + E;
  ush* Wkh = Wqh + WE;
  ush* Wvh = Wkh + WE;
  ush* Woh = Wvh + WE;
  float* stats = (float*)(Woh + WE);       // 256 floats
  float* tws   = stats + 4*NBH;

  hipMemsetAsync(stats, 0, 4*NBH*sizeof(float), stream);

  xconv<<<dim3(2048, 3), 256, 0, stream>>>(query, key, value, xqb, xkb, xvb);

  dim3 wb(32, 8), wg(32, 32, 4);
  wconv4<<<wg, wb, 0, stream>>>(Wq, Wk, Wv, Wo, Wqh, Wkh, Wvh, Woh);

  proj_qkv<<<768, 256, 0, stream>>>(xqb, xkb, xvb,
      Wqh, Wkh, Wvh, bq, bk, bv, Qi, Kbb, Vtb);

  attn_stats_mfma<<<512, 512, 0, stream>>>(Qi, Kbb, stats);
  time_mlp<<<1, 64, 0, stream>>>(stats, Wt1, bt1, Wt2, bt2, tws);
  attn_flash_mfma<<<512, 512, 0, stream>>>(Qi, Kbb, Vtb, tws, Aob);

  gemm_out<<<512, 256, 0, stream>>>(Aob, Woh, bo, (float*)d_out);
}

// Round 17
// 149.921 us; speedup vs baseline: 1.1001x; 1.0150x over previous
//
#include <hip/hip_runtime.h>
#include <hip/hip_bf16.h>
#include <math.h>

#define SS   1024
#define DM   1024
#define NH   16
#define DKH  64
#define NB   4
#define NBH  64

typedef unsigned short ush;
typedef unsigned int uint32;
typedef __attribute__((ext_vector_type(8))) short bf8_t;   // 8 bf16 = 4 VGPR
typedef __attribute__((ext_vector_type(4))) float f32x4;
#define MFMA16(a,b,c) __builtin_amdgcn_mfma_f32_16x16x32_bf16((a),(b),(c),0,0,0)

__device__ __forceinline__ ush f2bf(float x){ return __bfloat16_as_ushort(__float2bfloat16(x)); }
__device__ __forceinline__ float bf2f(ush h){ return __bfloat162float(__ushort_as_bfloat16(h)); }
__device__ __forceinline__ uint32 pk2(float a, float b){
  return (uint32)f2bf(a) | ((uint32)f2bf(b) << 16);
}
// pack value as (lo16<<16)|hi16
__device__ __forceinline__ uint32 pkhl(float v){
  ush h = f2bf(v);
  return (uint32)h | ((uint32)f2bf(v - bf2f(h)) << 16);
}
// extract hi/lo bf16 pairs from two interleaved uints (ulo = smaller d)
__device__ __forceinline__ uint32 prmh(uint32 uhi, uint32 ulo){
  return __builtin_amdgcn_perm(uhi, ulo, 0x05040100u);
}
__device__ __forceinline__ uint32 prml(uint32 uhi, uint32 ulo){
  return __builtin_amdgcn_perm(uhi, ulo, 0x07060302u);
}
// [rows][64]-ush tile, XOR swizzle on 16B chunks
__device__ __forceinline__ int swz8(int row, int chunk){
  return row*64 + (((chunk) ^ (row & 7)) << 3);
}
union U4B8 { uint4 u; bf8_t b; };

// ---- x fp32 -> bf16 (hi only)
__global__ __launch_bounds__(256) void xconv(
    const float* __restrict__ q, const float* __restrict__ k, const float* __restrict__ v,
    ush* __restrict__ xq, ush* __restrict__ xk, ush* __restrict__ xv)
{
  const float* src = (blockIdx.y==0)?q:(blockIdx.y==1)?k:v;
  ush* dst = (blockIdx.y==0)?xq:(blockIdx.y==1)?xk:xv;
  const size_t i = ((size_t)blockIdx.x*256 + threadIdx.x)*8;
  float4 a = *(const float4*)&src[i];
  float4 b = *(const float4*)&src[i+4];
  uint4 o;
  o.x = pk2(a.x, a.y); o.y = pk2(a.z, a.w);
  o.z = pk2(b.x, b.y); o.w = pk2(b.z, b.w);
  *(uint4*)&dst[i] = o;
}

// ---- weight convert: W (K x N) fp32 -> Wt (N x K) bf16 hi only
__global__ void wconv4(const float* __restrict__ W0, const float* __restrict__ W1,
                       const float* __restrict__ W2, const float* __restrict__ W3,
                       ush* __restrict__ H0, ush* __restrict__ H1,
                       ush* __restrict__ H2, ush* __restrict__ H3)
{
  __shared__ float T[32][33];
  const int tx = threadIdx.x, ty = threadIdx.y;    // (32,8)
  const int z = blockIdx.z;
  const float* W = (z==0)?W0:(z==1)?W1:(z==2)?W2:W3;
  ush* H = (z==0)?H0:(z==1)?H1:(z==2)?H2:H3;
  const int k0 = blockIdx.y*32, n0 = blockIdx.x*32;
  #pragma unroll
  for (int i = 0; i < 4; ++i){
    int r = ty + 8*i;
    T[r][tx] = W[(size_t)(k0 + r)*DM + n0 + tx];
  }
  __syncthreads();
  #pragma unroll
  for (int i = 0; i < 4; ++i){
    int r = ty + 8*i;              // n-local
    H[(size_t)(n0 + r)*DM + k0 + tx] = f2bf(T[tx][r]);
  }
}

// ---- fused Q/K/V projection: BK=32, 1-term (W hi), double-buffered LDS via
// global_load_lds width-16 with pre-swizzled per-lane SOURCE addresses.
__global__ __launch_bounds__(256) void proj_qkv(
    const ush* __restrict__ xq, const ush* __restrict__ xk, const ush* __restrict__ xv,
    const ush* __restrict__ Wqh, const ush* __restrict__ Wkh, const ush* __restrict__ Wvh,
    const float* __restrict__ bq, const float* __restrict__ bk,
    const float* __restrict__ bv,
    uint32* __restrict__ Qi, ush* __restrict__ Kb, ush* __restrict__ Vt)
{
  // staging: 2 buffers x (As 4096 | Bhs 4096) = 32 KB; V-epilogue 4*4224 ush
  __shared__ ush SMEM[16896];

  const int fid = blockIdx.x;
  const int glob = (fid & 7)*96 + (fid >> 3);  // XCD-contiguous chunks of 96
  const int z = glob >> 8, rem = glob & 255;
  const int m0 = (rem >> 3) * 128, n0 = (rem & 7) * 128;

  const ush* A  = (z==0) ? xq  : (z==1) ? xk  : xv;
  const ush* Bh = (z==0) ? Wqh : (z==1) ? Wkh : Wvh;

  const int tid = threadIdx.x;
  const int lane = tid & 63, w = tid >> 6;
  const int c = lane & 15, g = lane >> 4;
  const int wr = w >> 1, wc = w & 1;

  f32x4 acc[4][4];
  #pragma unroll
  for (int i = 0; i < 4; ++i)
    #pragma unroll
    for (int j = 0; j < 4; ++j) acc[i][j] = (f32x4){0.f,0.f,0.f,0.f};

  const int prow0 = w*16 + (lane >> 3), prow1 = prow0 + 8;
  const int jj = lane & 7;
  const int sg0 = jj ^ (prow0 & 7), sg1 = jj ^ (prow1 & 7);
  const size_t aoff0 = (size_t)(2*prow0 + (sg0 >> 2))*DM + (sg0 & 3)*8;
  const size_t aoff1 = (size_t)(2*prow1 + (sg1 >> 2))*DM + (sg1 & 3)*8;
  const ush* Aab = A  + (size_t)m0*DM;
  const ush* Bhb = Bh + (size_t)n0*DM;
  const int lb0 = w*1024, lb1 = w*1024 + 512;   // wave-uniform LDS bases (ush)

#define GLL(GP, LIDX) __builtin_amdgcn_global_load_lds( \
    (const __attribute__((address_space(1))) unsigned int*)(GP), \
    (__attribute__((address_space(3))) unsigned int*)(&SMEM[LIDX]), 16, 0, 0)

#define ISSUE_PROJ(BUFO, KT) do{ \
    GLL(Aab + aoff0 + (KT), (BUFO) + lb0); \
    GLL(Aab + aoff1 + (KT), (BUFO) + lb1); \
    GLL(Bhb + aoff0 + (KT), (BUFO) + 4096 + lb0); \
    GLL(Bhb + aoff1 + (KT), (BUFO) + 4096 + lb1); \
  }while(0)

  const int csw = (((4*(c & 1) + g) ^ ((c >> 1) & 7)) << 3);

  ISSUE_PROJ(0, 0);
  int cur = 0;
  for (int kt = 0; kt < DM; kt += 32){
    __syncthreads();                       // drains vmcnt -> buf[cur] ready
    if (kt + 32 < DM) ISSUE_PROJ((cur ^ 1)*8192, kt + 32);

    const ush* As  = SMEM + cur*8192;
    const ush* Bhs = As + 4096;

    bf8_t a_h[4];
    #pragma unroll
    for (int fm = 0; fm < 4; ++fm)
      a_h[fm] = *(const bf8_t*)&As[(32*wr + 8*fm + (c>>1))*64 + csw];
    __builtin_amdgcn_s_setprio(1);
    #pragma unroll
    for (int fn = 0; fn < 4; ++fn){
      bf8_t b_h = *(const bf8_t*)&Bhs[(32*wc + 8*fn + (c>>1))*64 + csw];
      #pragma unroll
      for (int fm = 0; fm < 4; ++fm)
        acc[fm][fn] = MFMA16(a_h[fm], b_h, acc[fm][fn]);
    }
    __builtin_amdgcn_s_setprio(0);
    cur ^= 1;
  }
#undef ISSUE_PROJ
#undef GLL

  if (z == 0){
    #pragma unroll
    for (int fm = 0; fm < 4; ++fm){
      #pragma unroll
      for (int fn = 0; fn < 4; ++fn){
        const int col = n0 + 64*wc + 16*fn + c;
        const float bb = bq[col];
        const int row0 = m0 + 64*wr + 16*fm + 4*g;
        const int hd = col >> 6, d = col & 63;
        #pragma unroll
        for (int r = 0; r < 4; ++r){
          const int row = row0 + r;
          const int b = row >> 10, s = row & 1023;
          Qi[((size_t)(b*NH + hd)*SS + s)*DKH + d] = pkhl(acc[fm][fn][r] + bb);
        }
      }
    }
  } else if (z == 1){
    #pragma unroll
    for (int fm = 0; fm < 4; ++fm){
      #pragma unroll
      for (int fn = 0; fn < 4; ++fn){
        const int col = n0 + 64*wc + 16*fn + c;
        const float bb = bk[col];
        const int row0 = m0 + 64*wr + 16*fm + 4*g;
        const int hd = col >> 6, d = col & 63;
        #pragma unroll
        for (int r = 0; r < 4; ++r){
          const int row = row0 + r;
          const int b = row >> 10, s = row & 1023;
          Kb[((size_t)(b*NH + hd)*SS + s)*DKH + d] = f2bf(acc[fm][fn][r] + bb);
        }
      }
    }
  } else {
    // V: transpose wave's 64(s) x 64(d) sub-tile through LDS -> coalesced (d,s)
    __syncthreads();                      // all waves done reading staging LDS
    ush* Vep = SMEM + w*4224;             // 64 rows(d) x 66 cols(s)
    #pragma unroll
    for (int fm = 0; fm < 4; ++fm){
      #pragma unroll
      for (int fn = 0; fn < 4; ++fn){
        const float bb = bv[n0 + 64*wc + 16*fn + c];
        #pragma unroll
        for (int r = 0; r < 4; ++r)
          Vep[(16*fn + c)*66 + 16*fm + 4*g + r] = f2bf(acc[fm][fn][r] + bb);
      }
    }
    const int b = m0 >> 10;
    const int s0 = (m0 & 1023) + 64*wr;
    const int hd = (n0 >> 6) + wc;
    const size_t vbase = ((size_t)(b*NH + hd))*DKH*SS;
    #pragma unroll
    for (int it = 0; it < 8; ++it){
      const int dr = 8*it + (lane >> 3);
      const int sc = (lane & 7)*8;
      uint4 vv = *(const uint4*)&Vep[dr*66 + sc];
      *(uint4*)&Vt[vbase + (size_t)dr*SS + s0 + sc] = vv;
    }
  }
}

// ---- output projection: C = A(bf16) @ Wo^T + bo, 128x64 tile, paired-row LDS
__global__ __launch_bounds__(256) void gemm_out(
    const ush* __restrict__ Abf, const ush* __restrict__ Bth,
    const float* __restrict__ bias, float* __restrict__ outf)
{
  __shared__ ush As[4096], Bs[2048];

  const int fid = blockIdx.x;
  const int glob = (fid & 7)*64 + (fid >> 3);
  const int m0 = (glob >> 4)*128, n0 = (glob & 15)*64;

  const int tid = threadIdx.x;
  const int lane = tid & 63, w = tid >> 6;
  const int c = lane & 15, g = lane >> 4;
  const int wr = w >> 1, wc = w & 1;

  f32x4 acc[4][2];
  #pragma unroll
  for (int i = 0; i < 4; ++i){ acc[i][0] = (f32x4){0,0,0,0}; acc[i][1] = (f32x4){0,0,0,0}; }

  const int prow = tid >> 3, ci = tid & 7;
  const int lr   = 2*prow + (ci >> 2);
  const int koff = (ci & 3) << 3;
  const int ws0  = prow*64 + ((ci ^ (prow & 7)) << 3);
  const int ws1  = ws0 + 32*64;
  const int csw  = (((4*(c & 1) + g) ^ ((c >> 1) & 7)) << 3);

  uint4 ar0, ar1, brr;
  #define ISSUE_OUT(KT) do{ \
    ar0 = *(const uint4*)(Abf + (size_t)(m0 + lr)*DM + (KT) + koff); \
    ar1 = *(const uint4*)(Abf + (size_t)(m0 + lr + 64)*DM + (KT) + koff); \
    brr = *(const uint4*)(Bth + (size_t)(n0 + lr)*DM + (KT) + koff); \
  }while(0)

  ISSUE_OUT(0);
  for (int kt = 0; kt < DM; kt += 32){
    *(uint4*)&As[ws0] = ar0;
    *(uint4*)&As[ws1] = ar1;
    if (lr < 64) *(uint4*)&Bs[ws0] = brr;
    __syncthreads();
    if (kt + 32 < DM) ISSUE_OUT(kt + 32);

    bf8_t a_h[4];
    #pragma unroll
    for (int fm = 0; fm < 4; ++fm)
      a_h[fm] = *(const bf8_t*)&As[(32*wr + 8*fm + (c>>1))*64 + csw];
    #pragma unroll
    for (int fn = 0; fn < 2; ++fn){
      bf8_t b_h = *(const bf8_t*)&Bs[(16*wc + 8*fn + (c>>1))*64 + csw];
      #pragma unroll
      for (int fm = 0; fm < 4; ++fm)
        acc[fm][fn] = MFMA16(a_h[fm], b_h, acc[fm][fn]);
    }
    __syncthreads();
  }
  #undef ISSUE_OUT

  #pragma unroll
  for (int fm = 0; fm < 4; ++fm){
    #pragma unroll
    for (int fn = 0; fn < 2; ++fn){
      const int col = n0 + 32*wc + 16*fn + c;
      const float bb = bias[col];
      const int row0 = m0 + 64*wr + 16*fm + 4*g;
      #pragma unroll
      for (int r = 0; r < 4; ++r)
        outf[(size_t)(row0 + r)*DM + col] = acc[fm][fn][r] + bb;
    }
  }
}

// ---- Stats pass: QBLK=128 (512 thr, 8 waves), KVBLK=64, 1-term QK (Qh),
// plain-bf16 K staging, prefetch. Atomic partial sums only (no election).
__global__ __launch_bounds__(512) void attn_stats_mfma(
    const uint32* __restrict__ Qi, const ush* __restrict__ Kb,
    float* __restrict__ stats)
{
  __shared__ ush Khs[64*64];
  __shared__ float red[8][3];
  const int tid = threadIdx.x, lane = tid & 63, w = tid >> 6;   // w 0..7
  const int c = lane & 15, g = lane >> 4;
  const int fid = blockIdx.x;
  const int glob = (fid & 7)*64 + (fid >> 3);     // 512 blocks, XCD-chunked
  const int bh = glob >> 3, q0 = (glob & 7)*128;

  bf8_t qh[2];
  {
    const size_t qoff = ((size_t)bh*SS + q0 + 16*w + c)*DKH + 8*g;
    uint4 u0 = *(const uint4*)(Qi + qoff);
    uint4 u1 = *(const uint4*)(Qi + qoff + 4);
    uint4 u2 = *(const uint4*)(Qi + qoff + 32);
    uint4 u3 = *(const uint4*)(Qi + qoff + 36);
    U4B8 t;
    t.u = (uint4){prmh(u0.y,u0.x), prmh(u0.w,u0.z), prmh(u1.y,u1.x), prmh(u1.w,u1.z)}; qh[0] = t.b;
    t.u = (uint4){prmh(u2.y,u2.x), prmh(u2.w,u2.z), prmh(u3.y,u3.x), prmh(u3.w,u3.z)}; qh[1] = t.b;
  }

  float ssum = 0.f, rmax = -1e30f, lsum = 0.f, l2sum = 0.f;
  const int rr0 = tid >> 3, ci = tid & 7;         // 64 rows x 8 chunks

  uint4 k0;
  #define ISSUE_ST(KC) do{ \
    k0 = *(const uint4*)(Kb + ((size_t)bh*SS + (KC)*64 + rr0)*DKH + ci*8); \
  }while(0)

  ISSUE_ST(0);
  for (int kc = 0; kc < 16; ++kc){
    *(uint4*)&Khs[swz8(rr0, ci)] = k0;
    __syncthreads();
    if (kc < 15) ISSUE_ST(kc + 1);

    f32x4 sa[4];
    #pragma unroll
    for (int fn = 0; fn < 4; ++fn) sa[fn] = (f32x4){0.f,0.f,0.f,0.f};
    __builtin_amdgcn_s_setprio(1);
    #pragma unroll
    for (int fn = 0; fn < 4; ++fn){
      #pragma unroll
      for (int ds = 0; ds < 2; ++ds){
        bf8_t ah = *(const bf8_t*)&Khs[swz8(16*fn + c, g + 4*ds)];
        sa[fn] = MFMA16(ah, qh[ds], sa[fn]);      // 1-term: Kh . Qh
      }
    }
    __builtin_amdgcn_s_setprio(0);
    #pragma unroll
    for (int fn = 0; fn < 4; ++fn){
      #pragma unroll
      for (int r = 0; r < 4; ++r){
        float s = sa[fn][r] * 0.125f;
        ssum += s;
        rmax = fmaxf(rmax, s);
        float e = exp2f(s * 0.7213475204f);       // exp(s/2); |s|<50 fp32-safe
        lsum += e;
        l2sum = fmaf(e, e, l2sum);
      }
    }
    __syncthreads();
  }
  #undef ISSUE_ST

  rmax  = fmaxf(rmax, __shfl_xor(rmax, 16, 64));
  rmax  = fmaxf(rmax, __shfl_xor(rmax, 32, 64));
  lsum  += __shfl_xor(lsum, 16, 64);   lsum  += __shfl_xor(lsum, 32, 64);
  l2sum += __shfl_xor(l2sum, 16, 64);  l2sum += __shfl_xor(l2sum, 32, 64);
  float varc = (l2sum/(lsum*lsum) - (1.0f/1024.f)) * (1.0f/1023.f);
  float a0 = ssum, a1 = rmax * 0.25f, a2 = varc * 0.25f;
  #pragma unroll
  for (int off = 1; off < 64; off <<= 1){
    a0 += __shfl_xor(a0, off, 64);
    a1 += __shfl_xor(a1, off, 64);
    a2 += __shfl_xor(a2, off, 64);
  }
  if (lane == 0){ red[w][0] = a0; red[w][1] = a1; red[w][2] = a2; }
  __syncthreads();
  if (tid == 0){
    float r0 = 0.f, r1 = 0.f, r2 = 0.f;
    #pragma unroll
    for (int i = 0; i < 8; ++i){ r0 += red[i][0]; r1 += red[i][1]; r2 += red[i][2]; }
    atomicAdd(&stats[bh*4+0], r0);
    atomicAdd(&stats[bh*4+1], r1);
    atomicAdd(&stats[bh*4+2], r2);
  }
}

// ---- Flash pass: QBLK=128 (512 thr), KVBLK=64 (16 iters), swapped QK^T
// 2-term, plain-bf16 K, exp2, defer-max, swizzled LDS, prefetch. LDS = 32 KB.
// Time-MLP folded into the prologue (stats finalized at kernel boundary;
// all blocks compute t deterministically from identical inputs).
__global__ __launch_bounds__(512) void attn_flash_mfma(
    const uint32* __restrict__ Qi, const ush* __restrict__ Kb,
    const ush* __restrict__ Vt, const float* __restrict__ stats,
    const float* __restrict__ Wt1, const float* __restrict__ bt1,
    const float* __restrict__ Wt2, const float* __restrict__ bt2,
    ush* __restrict__ aout)
{
  __shared__ ush Khs[64*64], Vts[64*64], Ps[128*64];
  const int tid = threadIdx.x, lane = tid & 63, w = tid >> 6;   // w 0..7
  const int c = lane & 15, g = lane >> 4;
  const int fid = blockIdx.x;
  const int glob = (fid & 7)*64 + (fid >> 3);     // 512 blocks, XCD-chunked
  const int bh = glob >> 3, q0 = (glob & 7)*128;

  // ---- inline time-MLP (redundant per thread; deterministic)
  float tsc2;
  {
    float mean = fminf(fmaxf(stats[bh*4+0] * (1.f/(1024.f*1024.f)), -10.f), 10.f);
    float mx   = fminf(fmaxf(stats[bh*4+1] * (1.f/1024.f), -10.f), 10.f);
    float ent  = fminf(fmaxf(stats[bh*4+2] * (1.f/1024.f),   0.f),  1.f);
    float raw = bt2[0];
    #pragma unroll
    for (int j = 0; j < 16; ++j){
      float h = tanhf(mean*Wt1[j] + mx*Wt1[16+j] + ent*Wt1[32+j] + bt1[j]);
      raw += h * Wt2[j];
    }
    float sig = 1.f / (1.f + expf(-raw));
    float t = 0.01f + sig * 1.99f;
    t = fminf(fminf(fmaxf(t, 0.01f), 2.0f), 0.85f);
    tsc2 = (0.5f / t) * 1.44269504f;              // exp2 domain
  }

  bf8_t qh[2], ql[2];
  {
    const size_t qoff = ((size_t)bh*SS + q0 + 16*w + c)*DKH + 8*g;
    uint4 u0 = *(const uint4*)(Qi + qoff);
    uint4 u1 = *(const uint4*)(Qi + qoff + 4);
    uint4 u2 = *(const uint4*)(Qi + qoff + 32);
    uint4 u3 = *(const uint4*)(Qi + qoff + 36);
    U4B8 t;
    t.u = (uint4){prmh(u0.y,u0.x), prmh(u0.w,u0.z), prmh(u1.y,u1.x), prmh(u1.w,u1.z)}; qh[0] = t.b;
    t.u = (uint4){prml(u0.y,u0.x), prml(u0.w,u0.z), prml(u1.y,u1.x), prml(u1.w,u1.z)}; ql[0] = t.b;
    t.u = (uint4){prmh(u2.y,u2.x), prmh(u2.w,u2.z), prmh(u3.y,u3.x), prmh(u3.w,u3.z)}; qh[1] = t.b;
    t.u = (uint4){prml(u2.y,u2.x), prml(u2.w,u2.z), prml(u3.y,u3.x), prml(u3.w,u3.z)}; ql[1] = t.b;
  }

  f32x4 o[4];
  #pragma unroll
  for (int i = 0; i < 4; ++i) o[i] = (f32x4){0.f,0.f,0.f,0.f};
  float m = -INFINITY, lpart = 0.f;

  const int rr0 = tid >> 3, ci = tid & 7;         // 64 rows x 8 chunks

  uint4 k0, vr0;
  #define ISSUE_FL(KC) do{ \
    k0  = *(const uint4*)(Kb + ((size_t)bh*SS + (KC)*64 + rr0)*DKH + ci*8); \
    vr0 = *(const uint4*)(Vt + ((size_t)bh*DKH + rr0)*SS + (KC)*64 + ci*8); \
  }while(0)

  ISSUE_FL(0);
  for (int kc = 0; kc < 16; ++kc){
    *(uint4*)&Khs[swz8(rr0, ci)] = k0;
    *(uint4*)&Vts[swz8(rr0, ci)] = vr0;
    __syncthreads();
    if (kc < 15) ISSUE_FL(kc + 1);

    f32x4 sa[4];
    #pragma unroll
    for (int fn = 0; fn < 4; ++fn) sa[fn] = (f32x4){0.f,0.f,0.f,0.f};
    __builtin_amdgcn_s_setprio(1);
    #pragma unroll
    for (int fn = 0; fn < 4; ++fn){
      #pragma unroll
      for (int ds = 0; ds < 2; ++ds){
        bf8_t ah = *(const bf8_t*)&Khs[swz8(16*fn + c, g + 4*ds)];
        sa[fn] = MFMA16(ah, qh[ds], sa[fn]);   // 2-term: Kh . (Qh + Ql)
        sa[fn] = MFMA16(ah, ql[ds], sa[fn]);
      }
    }
    __builtin_amdgcn_s_setprio(0);

    // lane-local max over own 16 kv; shuffles only in the rare rescale path
    float pmaxr = -1e30f;
    #pragma unroll
    for (int fn = 0; fn < 4; ++fn)
      #pragma unroll
      for (int r = 0; r < 4; ++r) pmaxr = fmaxf(pmaxr, sa[fn][r]);

    if (!__all(pmaxr * tsc2 <= m + 30.f)){     // fires ~once (kc=0)
      pmaxr = fmaxf(pmaxr, __shfl_xor(pmaxr, 16, 64));
      pmaxr = fmaxf(pmaxr, __shfl_xor(pmaxr, 32, 64));
      float pmax = pmaxr * tsc2;
      float mn = fmaxf(m, pmax);
      float sc = exp2f(m - mn);
      m = mn;
      lpart *= sc;
      #pragma unroll
      for (int r = 0; r < 4; ++r){
        float so = __shfl(sc, 4*g + r, 16);    // sc of q-row 4g+r (c'=4g+r)
        #pragma unroll
        for (int fn = 0; fn < 4; ++fn) o[fn][r] *= so;
      }
    }

    const float mneg = -m;
    #pragma unroll
    for (int fn = 0; fn < 4; ++fn){
      float e0 = exp2f(fmaf(sa[fn][0], tsc2, mneg));
      float e1 = exp2f(fmaf(sa[fn][1], tsc2, mneg));
      float e2 = exp2f(fmaf(sa[fn][2], tsc2, mneg));
      float e3 = exp2f(fmaf(sa[fn][3], tsc2, mneg));
      lpart += (e0 + e1) + (e2 + e3);
      uint2 pk;
      pk.x = pk2(e0, e1);
      pk.y = pk2(e2, e3);
      const int q4 = 4*fn + g;
      const int addr = (16*w + c)*64 + ((((q4 >> 1) ^ (c & 7)) << 3)) + (q4 & 1)*4;
      *(uint2*)&Ps[addr] = pk;
    }

    __builtin_amdgcn_s_setprio(1);
    #pragma unroll
    for (int kvs = 0; kvs < 2; ++kvs){
      bf8_t pa = *(const bf8_t*)&Ps[swz8(16*w + c, g + 4*kvs)];
      #pragma unroll
      for (int fn = 0; fn < 4; ++fn){
        bf8_t vb = *(const bf8_t*)&Vts[swz8(16*fn + c, g + 4*kvs)];
        o[fn] = MFMA16(pa, vb, o[fn]);
      }
    }
    __builtin_amdgcn_s_setprio(0);
    __syncthreads();
  }
  #undef ISSUE_FL

  lpart += __shfl_xor(lpart, 16, 64);
  lpart += __shfl_xor(lpart, 32, 64);
  const int b = bh >> 4, hd = bh & 15;
  #pragma unroll
  for (int r = 0; r < 4; ++r){
    float linv = 1.f / __shfl(lpart, 4*g + r, 16);   // l of q-row 4g+r
    const int q = q0 + 16*w + 4*g + r;
    #pragma unroll
    for (int fn = 0; fn < 4; ++fn)
      aout[((size_t)(b*SS + q))*DM + hd*DKH + 16*fn + c] = f2bf(o[fn][r] * linv);
  }
}

extern "C" void kernel_launch(void* const* d_in, const int* in_sizes, int n_in,
                              void* d_out, int out_size, void* d_ws, size_t ws_size,
                              hipStream_t stream)
{
  const float* query = (const float*)d_in[0];
  const float* key   = (const float*)d_in[1];
  const float* value = (const float*)d_in[2];
  const float* Wq = (const float*)d_in[3];
  const float* bq = (const float*)d_in[4];
  const float* Wk = (const float*)d_in[5];
  const float* bk = (const float*)d_in[6];
  const float* Wv = (const float*)d_in[7];
  const float* bv = (const float*)d_in[8];
  const float* Wo = (const float*)d_in[9];
  const float* bo = (const float*)d_in[10];
  const float* Wt1 = (const float*)d_in[11];
  const float* bt1 = (const float*)d_in[12];
  const float* Wt2 = (const float*)d_in[13];
  const float* bt2 = (const float*)d_in[14];

  const size_t E = (size_t)NB*SS*DM;       // 4,194,304
  const size_t WE = (size_t)DM*DM;

  uint32* Qi  = (uint32*)d_ws;             // E uint32 (hi|lo interleaved)
  ush* Kbb = (ush*)(Qi + E);               // E ush (plain bf16)
  ush* Vtb = Kbb + E;                      // E ush (b*16+h, dk, s)
  ush* Aob = Vtb + E;                      // E ush  -- also aliased as xqb
  ush* xqb = Aob;                          // alias: consumed before Aob written
  ush* xkb = Aob + E;
  ush* xvb = xkb + E;
  ush* Wqh = xvb + E;
  ush* Wkh = Wqh + WE;
  ush* Wvh = Wkh + WE;
  ush* Woh = Wvh + WE;
  float* stats = (float*)(Woh + WE);       // 256 floats

  hipMemsetAsync(stats, 0, 4*NBH*sizeof(float), stream);

  xconv<<<dim3(2048, 3), 256, 0, stream>>>(query, key, value, xqb, xkb, xvb);

  dim3 wb(32, 8), wg(32, 32, 4);
  wconv4<<<wg, wb, 0, stream>>>(Wq, Wk, Wv, Wo, Wqh, Wkh, Wvh, Woh);

  proj_qkv<<<768, 256, 0, stream>>>(xqb, xkb, xvb,
      Wqh, Wkh, Wvh, bq, bk, bv, Qi, Kbb, Vtb);

  attn_stats_mfma<<<512, 512, 0, stream>>>(Qi, Kbb, stats);
  attn_flash_mfma<<<512, 512, 0, stream>>>(Qi, Kbb, Vtb, stats,
      Wt1, bt1, Wt2, bt2, Aob);

  gemm_out<<<512, 256, 0, stream>>>(Aob, Woh, bo, (float*)d_out);
}

// Round 18
// 149.003 us; speedup vs baseline: 1.1068x; 1.0062x over previous
//
#include <hip/hip_runtime.h>
#include <hip/hip_bf16.h>
#include <math.h>

#define SS   1024
#define DM   1024
#define NH   16
#define DKH  64
#define NB   4
#define NBH  64

typedef unsigned short ush;
typedef unsigned int uint32;
typedef __attribute__((ext_vector_type(8))) short bf8_t;   // 8 bf16 = 4 VGPR
typedef __attribute__((ext_vector_type(4))) float f32x4;
#define MFMA16(a,b,c) __builtin_amdgcn_mfma_f32_16x16x32_bf16((a),(b),(c),0,0,0)

__device__ __forceinline__ ush f2bf(float x){ return __bfloat16_as_ushort(__float2bfloat16(x)); }
__device__ __forceinline__ float bf2f(ush h){ return __bfloat162float(__ushort_as_bfloat16(h)); }
__device__ __forceinline__ uint32 pk2(float a, float b){
  return (uint32)f2bf(a) | ((uint32)f2bf(b) << 16);
}
// pack value as (lo16<<16)|hi16
__device__ __forceinline__ uint32 pkhl(float v){
  ush h = f2bf(v);
  return (uint32)h | ((uint32)f2bf(v - bf2f(h)) << 16);
}
// extract hi/lo bf16 pairs from two interleaved uints (ulo = smaller d)
__device__ __forceinline__ uint32 prmh(uint32 uhi, uint32 ulo){
  return __builtin_amdgcn_perm(uhi, ulo, 0x05040100u);
}
__device__ __forceinline__ uint32 prml(uint32 uhi, uint32 ulo){
  return __builtin_amdgcn_perm(uhi, ulo, 0x07060302u);
}
// [rows][64]-ush tile, XOR swizzle on 16B chunks
__device__ __forceinline__ int swz8(int row, int chunk){
  return row*64 + (((chunk) ^ (row & 7)) << 3);
}
union U4B8 { uint4 u; bf8_t b; };

// ---- x fp32 -> bf16 (hi only)
__global__ __launch_bounds__(256) void xconv(
    const float* __restrict__ q, const float* __restrict__ k, const float* __restrict__ v,
    ush* __restrict__ xq, ush* __restrict__ xk, ush* __restrict__ xv)
{
  const float* src = (blockIdx.y==0)?q:(blockIdx.y==1)?k:v;
  ush* dst = (blockIdx.y==0)?xq:(blockIdx.y==1)?xk:xv;
  const size_t i = ((size_t)blockIdx.x*256 + threadIdx.x)*8;
  float4 a = *(const float4*)&src[i];
  float4 b = *(const float4*)&src[i+4];
  uint4 o;
  o.x = pk2(a.x, a.y); o.y = pk2(a.z, a.w);
  o.z = pk2(b.x, b.y); o.w = pk2(b.z, b.w);
  *(uint4*)&dst[i] = o;
}

// ---- weight convert: W (K x N) fp32 -> Wt (N x K) bf16 hi only
__global__ void wconv4(const float* __restrict__ W0, const float* __restrict__ W1,
                       const float* __restrict__ W2, const float* __restrict__ W3,
                       ush* __restrict__ H0, ush* __restrict__ H1,
                       ush* __restrict__ H2, ush* __restrict__ H3)
{
  __shared__ float T[32][33];
  const int tx = threadIdx.x, ty = threadIdx.y;    // (32,8)
  const int z = blockIdx.z;
  const float* W = (z==0)?W0:(z==1)?W1:(z==2)?W2:W3;
  ush* H = (z==0)?H0:(z==1)?H1:(z==2)?H2:H3;
  const int k0 = blockIdx.y*32, n0 = blockIdx.x*32;
  #pragma unroll
  for (int i = 0; i < 4; ++i){
    int r = ty + 8*i;
    T[r][tx] = W[(size_t)(k0 + r)*DM + n0 + tx];
  }
  __syncthreads();
  #pragma unroll
  for (int i = 0; i < 4; ++i){
    int r = ty + 8*i;              // n-local
    H[(size_t)(n0 + r)*DM + k0 + tx] = f2bf(T[tx][r]);
  }
}

// ---- fused Q/K/V projection: BK=32, 1-term (W hi), double-buffered LDS via
// global_load_lds width-16 with pre-swizzled per-lane SOURCE addresses.
__global__ __launch_bounds__(256) void proj_qkv(
    const ush* __restrict__ xq, const ush* __restrict__ xk, const ush* __restrict__ xv,
    const ush* __restrict__ Wqh, const ush* __restrict__ Wkh, const ush* __restrict__ Wvh,
    const float* __restrict__ bq, const float* __restrict__ bk,
    const float* __restrict__ bv,
    uint32* __restrict__ Qi, ush* __restrict__ Kb, ush* __restrict__ Vt)
{
  // staging: 2 buffers x (As 4096 | Bhs 4096) = 32 KB; V-epilogue 4*4224 ush
  __shared__ ush SMEM[16896];

  const int fid = blockIdx.x;
  const int glob = (fid & 7)*96 + (fid >> 3);  // XCD-contiguous chunks of 96
  const int z = glob >> 8, rem = glob & 255;
  const int m0 = (rem >> 3) * 128, n0 = (rem & 7) * 128;

  const ush* A  = (z==0) ? xq  : (z==1) ? xk  : xv;
  const ush* Bh = (z==0) ? Wqh : (z==1) ? Wkh : Wvh;

  const int tid = threadIdx.x;
  const int lane = tid & 63, w = tid >> 6;
  const int c = lane & 15, g = lane >> 4;
  const int wr = w >> 1, wc = w & 1;

  f32x4 acc[4][4];
  #pragma unroll
  for (int i = 0; i < 4; ++i)
    #pragma unroll
    for (int j = 0; j < 4; ++j) acc[i][j] = (f32x4){0.f,0.f,0.f,0.f};

  const int prow0 = w*16 + (lane >> 3), prow1 = prow0 + 8;
  const int jj = lane & 7;
  const int sg0 = jj ^ (prow0 & 7), sg1 = jj ^ (prow1 & 7);
  const size_t aoff0 = (size_t)(2*prow0 + (sg0 >> 2))*DM + (sg0 & 3)*8;
  const size_t aoff1 = (size_t)(2*prow1 + (sg1 >> 2))*DM + (sg1 & 3)*8;
  const ush* Aab = A  + (size_t)m0*DM;
  const ush* Bhb = Bh + (size_t)n0*DM;
  const int lb0 = w*1024, lb1 = w*1024 + 512;   // wave-uniform LDS bases (ush)

#define GLL(GP, LIDX) __builtin_amdgcn_global_load_lds( \
    (const __attribute__((address_space(1))) unsigned int*)(GP), \
    (__attribute__((address_space(3))) unsigned int*)(&SMEM[LIDX]), 16, 0, 0)

#define ISSUE_PROJ(BUFO, KT) do{ \
    GLL(Aab + aoff0 + (KT), (BUFO) + lb0); \
    GLL(Aab + aoff1 + (KT), (BUFO) + lb1); \
    GLL(Bhb + aoff0 + (KT), (BUFO) + 4096 + lb0); \
    GLL(Bhb + aoff1 + (KT), (BUFO) + 4096 + lb1); \
  }while(0)

  const int csw = (((4*(c & 1) + g) ^ ((c >> 1) & 7)) << 3);

  ISSUE_PROJ(0, 0);
  int cur = 0;
  for (int kt = 0; kt < DM; kt += 32){
    __syncthreads();                       // drains vmcnt -> buf[cur] ready
    if (kt + 32 < DM) ISSUE_PROJ((cur ^ 1)*8192, kt + 32);

    const ush* As  = SMEM + cur*8192;
    const ush* Bhs = As + 4096;

    bf8_t a_h[4];
    #pragma unroll
    for (int fm = 0; fm < 4; ++fm)
      a_h[fm] = *(const bf8_t*)&As[(32*wr + 8*fm + (c>>1))*64 + csw];
    __builtin_amdgcn_s_setprio(1);
    #pragma unroll
    for (int fn = 0; fn < 4; ++fn){
      bf8_t b_h = *(const bf8_t*)&Bhs[(32*wc + 8*fn + (c>>1))*64 + csw];
      #pragma unroll
      for (int fm = 0; fm < 4; ++fm)
        acc[fm][fn] = MFMA16(a_h[fm], b_h, acc[fm][fn]);
    }
    __builtin_amdgcn_s_setprio(0);
    cur ^= 1;
  }
#undef ISSUE_PROJ
#undef GLL

  if (z == 0){
    #pragma unroll
    for (int fm = 0; fm < 4; ++fm){
      #pragma unroll
      for (int fn = 0; fn < 4; ++fn){
        const int col = n0 + 64*wc + 16*fn + c;
        const float bb = bq[col];
        const int row0 = m0 + 64*wr + 16*fm + 4*g;
        const int hd = col >> 6, d = col & 63;
        #pragma unroll
        for (int r = 0; r < 4; ++r){
          const int row = row0 + r;
          const int b = row >> 10, s = row & 1023;
          Qi[((size_t)(b*NH + hd)*SS + s)*DKH + d] = pkhl(acc[fm][fn][r] + bb);
        }
      }
    }
  } else if (z == 1){
    #pragma unroll
    for (int fm = 0; fm < 4; ++fm){
      #pragma unroll
      for (int fn = 0; fn < 4; ++fn){
        const int col = n0 + 64*wc + 16*fn + c;
        const float bb = bk[col];
        const int row0 = m0 + 64*wr + 16*fm + 4*g;
        const int hd = col >> 6, d = col & 63;
        #pragma unroll
        for (int r = 0; r < 4; ++r){
          const int row = row0 + r;
          const int b = row >> 10, s = row & 1023;
          Kb[((size_t)(b*NH + hd)*SS + s)*DKH + d] = f2bf(acc[fm][fn][r] + bb);
        }
      }
    }
  } else {
    // V: transpose wave's 64(s) x 64(d) sub-tile through LDS -> coalesced (d,s)
    __syncthreads();                      // all waves done reading staging LDS
    ush* Vep = SMEM + w*4224;             // 64 rows(d) x 66 cols(s)
    #pragma unroll
    for (int fm = 0; fm < 4; ++fm){
      #pragma unroll
      for (int fn = 0; fn < 4; ++fn){
        const float bb = bv[n0 + 64*wc + 16*fn + c];
        #pragma unroll
        for (int r = 0; r < 4; ++r)
          Vep[(16*fn + c)*66 + 16*fm + 4*g + r] = f2bf(acc[fm][fn][r] + bb);
      }
    }
    const int b = m0 >> 10;
    const int s0 = (m0 & 1023) + 64*wr;
    const int hd = (n0 >> 6) + wc;
    const size_t vbase = ((size_t)(b*NH + hd))*DKH*SS;
    #pragma unroll
    for (int it = 0; it < 8; ++it){
      const int dr = 8*it + (lane >> 3);
      const int sc = (lane & 7)*8;
      uint4 vv = *(const uint4*)&Vep[dr*66 + sc];
      *(uint4*)&Vt[vbase + (size_t)dr*SS + s0 + sc] = vv;
    }
  }
}

// ---- output projection: C = A(bf16) @ Wo^T + bo, 128x64 tile, paired-row LDS
__global__ __launch_bounds__(256) void gemm_out(
    const ush* __restrict__ Abf, const ush* __restrict__ Bth,
    const float* __restrict__ bias, float* __restrict__ outf)
{
  __shared__ ush As[4096], Bs[2048];

  const int fid = blockIdx.x;
  const int glob = (fid & 7)*64 + (fid >> 3);
  const int m0 = (glob >> 4)*128, n0 = (glob & 15)*64;

  const int tid = threadIdx.x;
  const int lane = tid & 63, w = tid >> 6;
  const int c = lane & 15, g = lane >> 4;
  const int wr = w >> 1, wc = w & 1;

  f32x4 acc[4][2];
  #pragma unroll
  for (int i = 0; i < 4; ++i){ acc[i][0] = (f32x4){0,0,0,0}; acc[i][1] = (f32x4){0,0,0,0}; }

  const int prow = tid >> 3, ci = tid & 7;
  const int lr   = 2*prow + (ci >> 2);
  const int koff = (ci & 3) << 3;
  const int ws0  = prow*64 + ((ci ^ (prow & 7)) << 3);
  const int ws1  = ws0 + 32*64;
  const int csw  = (((4*(c & 1) + g) ^ ((c >> 1) & 7)) << 3);

  uint4 ar0, ar1, brr;
  #define ISSUE_OUT(KT) do{ \
    ar0 = *(const uint4*)(Abf + (size_t)(m0 + lr)*DM + (KT) + koff); \
    ar1 = *(const uint4*)(Abf + (size_t)(m0 + lr + 64)*DM + (KT) + koff); \
    brr = *(const uint4*)(Bth + (size_t)(n0 + lr)*DM + (KT) + koff); \
  }while(0)

  ISSUE_OUT(0);
  for (int kt = 0; kt < DM; kt += 32){
    *(uint4*)&As[ws0] = ar0;
    *(uint4*)&As[ws1] = ar1;
    if (lr < 64) *(uint4*)&Bs[ws0] = brr;
    __syncthreads();
    if (kt + 32 < DM) ISSUE_OUT(kt + 32);

    bf8_t a_h[4];
    #pragma unroll
    for (int fm = 0; fm < 4; ++fm)
      a_h[fm] = *(const bf8_t*)&As[(32*wr + 8*fm + (c>>1))*64 + csw];
    #pragma unroll
    for (int fn = 0; fn < 2; ++fn){
      bf8_t b_h = *(const bf8_t*)&Bs[(16*wc + 8*fn + (c>>1))*64 + csw];
      #pragma unroll
      for (int fm = 0; fm < 4; ++fm)
        acc[fm][fn] = MFMA16(a_h[fm], b_h, acc[fm][fn]);
    }
    __syncthreads();
  }
  #undef ISSUE_OUT

  #pragma unroll
  for (int fm = 0; fm < 4; ++fm){
    #pragma unroll
    for (int fn = 0; fn < 2; ++fn){
      const int col = n0 + 32*wc + 16*fn + c;
      const float bb = bias[col];
      const int row0 = m0 + 64*wr + 16*fm + 4*g;
      #pragma unroll
      for (int r = 0; r < 4; ++r)
        outf[(size_t)(row0 + r)*DM + col] = acc[fm][fn][r] + bb;
    }
  }
}

// ---- Stats pass: QBLK=128 (512 thr, 8 waves), KVBLK=64, 1-term QK (Qh),
// plain-bf16 K staging, prefetch. Atomic partial sums only (no election).
__global__ __launch_bounds__(512) void attn_stats_mfma(
    const uint32* __restrict__ Qi, const ush* __restrict__ Kb,
    float* __restrict__ stats)
{
  __shared__ ush Khs[64*64];
  __shared__ float red[8][3];
  const int tid = threadIdx.x, lane = tid & 63, w = tid >> 6;   // w 0..7
  const int c = lane & 15, g = lane >> 4;
  const int fid = blockIdx.x;
  const int glob = (fid & 7)*64 + (fid >> 3);     // 512 blocks, XCD-chunked
  const int bh = glob >> 3, q0 = (glob & 7)*128;

  bf8_t qh[2];
  {
    const size_t qoff = ((size_t)bh*SS + q0 + 16*w + c)*DKH + 8*g;
    uint4 u0 = *(const uint4*)(Qi + qoff);
    uint4 u1 = *(const uint4*)(Qi + qoff + 4);
    uint4 u2 = *(const uint4*)(Qi + qoff + 32);
    uint4 u3 = *(const uint4*)(Qi + qoff + 36);
    U4B8 t;
    t.u = (uint4){prmh(u0.y,u0.x), prmh(u0.w,u0.z), prmh(u1.y,u1.x), prmh(u1.w,u1.z)}; qh[0] = t.b;
    t.u = (uint4){prmh(u2.y,u2.x), prmh(u2.w,u2.z), prmh(u3.y,u3.x), prmh(u3.w,u3.z)}; qh[1] = t.b;
  }

  float ssum = 0.f, rmax = -1e30f, lsum = 0.f, l2sum = 0.f;
  const int rr0 = tid >> 3, ci = tid & 7;         // 64 rows x 8 chunks

  uint4 k0;
  #define ISSUE_ST(KC) do{ \
    k0 = *(const uint4*)(Kb + ((size_t)bh*SS + (KC)*64 + rr0)*DKH + ci*8); \
  }while(0)

  ISSUE_ST(0);
  for (int kc = 0; kc < 16; ++kc){
    *(uint4*)&Khs[swz8(rr0, ci)] = k0;
    __syncthreads();
    if (kc < 15) ISSUE_ST(kc + 1);

    f32x4 sa[4];
    #pragma unroll
    for (int fn = 0; fn < 4; ++fn) sa[fn] = (f32x4){0.f,0.f,0.f,0.f};
    __builtin_amdgcn_s_setprio(1);
    #pragma unroll
    for (int fn = 0; fn < 4; ++fn){
      #pragma unroll
      for (int ds = 0; ds < 2; ++ds){
        bf8_t ah = *(const bf8_t*)&Khs[swz8(16*fn + c, g + 4*ds)];
        sa[fn] = MFMA16(ah, qh[ds], sa[fn]);      // 1-term: Kh . Qh
      }
    }
    __builtin_amdgcn_s_setprio(0);
    #pragma unroll
    for (int fn = 0; fn < 4; ++fn){
      #pragma unroll
      for (int r = 0; r < 4; ++r){
        float s = sa[fn][r] * 0.125f;
        ssum += s;
        rmax = fmaxf(rmax, s);
        float e = exp2f(s * 0.7213475204f);       // exp(s/2); |s|<50 fp32-safe
        lsum += e;
        l2sum = fmaf(e, e, l2sum);
      }
    }
    __syncthreads();
  }
  #undef ISSUE_ST

  rmax  = fmaxf(rmax, __shfl_xor(rmax, 16, 64));
  rmax  = fmaxf(rmax, __shfl_xor(rmax, 32, 64));
  lsum  += __shfl_xor(lsum, 16, 64);   lsum  += __shfl_xor(lsum, 32, 64);
  l2sum += __shfl_xor(l2sum, 16, 64);  l2sum += __shfl_xor(l2sum, 32, 64);
  float varc = (l2sum/(lsum*lsum) - (1.0f/1024.f)) * (1.0f/1023.f);
  float a0 = ssum, a1 = rmax * 0.25f, a2 = varc * 0.25f;
  #pragma unroll
  for (int off = 1; off < 64; off <<= 1){
    a0 += __shfl_xor(a0, off, 64);
    a1 += __shfl_xor(a1, off, 64);
    a2 += __shfl_xor(a2, off, 64);
  }
  if (lane == 0){ red[w][0] = a0; red[w][1] = a1; red[w][2] = a2; }
  __syncthreads();
  if (tid == 0){
    float r0 = 0.f, r1 = 0.f, r2 = 0.f;
    #pragma unroll
    for (int i = 0; i < 8; ++i){ r0 += red[i][0]; r1 += red[i][1]; r2 += red[i][2]; }
    atomicAdd(&stats[bh*4+0], r0);
    atomicAdd(&stats[bh*4+1], r1);
    atomicAdd(&stats[bh*4+2], r2);
  }
}

// ---- Flash pass: QBLK=128 (512 thr), KVBLK=64 (16 iters), swapped QK^T
// 2-term, plain-bf16 K, exp2, defer-max, swizzled LDS, prefetch. LDS = 32 KB.
// Time-MLP in prologue, lane-parallel (16 lanes, 1 tanh each) + LDS broadcast.
__global__ __launch_bounds__(512) void attn_flash_mfma(
    const uint32* __restrict__ Qi, const ush* __restrict__ Kb,
    const ush* __restrict__ Vt, const float* __restrict__ stats,
    const float* __restrict__ Wt1, const float* __restrict__ bt1,
    const float* __restrict__ Wt2, const float* __restrict__ bt2,
    ush* __restrict__ aout)
{
  __shared__ ush Khs[64*64], Vts[64*64], Ps[128*64];
  __shared__ float tshare;
  const int tid = threadIdx.x, lane = tid & 63, w = tid >> 6;   // w 0..7
  const int c = lane & 15, g = lane >> 4;
  const int fid = blockIdx.x;
  const int glob = (fid & 7)*64 + (fid >> 3);     // 512 blocks, XCD-chunked
  const int bh = glob >> 3, q0 = (glob & 7)*128;

  // ---- lane-parallel time-MLP: lane j of wave 0 computes hidden unit j
  if (tid < 16){
    float mean = fminf(fmaxf(stats[bh*4+0] * (1.f/(1024.f*1024.f)), -10.f), 10.f);
    float mx   = fminf(fmaxf(stats[bh*4+1] * (1.f/1024.f), -10.f), 10.f);
    float ent  = fminf(fmaxf(stats[bh*4+2] * (1.f/1024.f),   0.f),  1.f);
    float h = tanhf(mean*Wt1[tid] + mx*Wt1[16+tid] + ent*Wt1[32+tid] + bt1[tid])
              * Wt2[tid];
    h += __shfl_xor(h, 1, 64);
    h += __shfl_xor(h, 2, 64);
    h += __shfl_xor(h, 4, 64);
    h += __shfl_xor(h, 8, 64);
    if (tid == 0){
      float raw = h + bt2[0];
      float sig = 1.f / (1.f + expf(-raw));
      float t = 0.01f + sig * 1.99f;
      t = fminf(fminf(fmaxf(t, 0.01f), 2.0f), 0.85f);
      tshare = (0.5f / t) * 1.44269504f;          // exp2 domain
    }
  }

  bf8_t qh[2], ql[2];
  {
    const size_t qoff = ((size_t)bh*SS + q0 + 16*w + c)*DKH + 8*g;
    uint4 u0 = *(const uint4*)(Qi + qoff);
    uint4 u1 = *(const uint4*)(Qi + qoff + 4);
    uint4 u2 = *(const uint4*)(Qi + qoff + 32);
    uint4 u3 = *(const uint4*)(Qi + qoff + 36);
    U4B8 t;
    t.u = (uint4){prmh(u0.y,u0.x), prmh(u0.w,u0.z), prmh(u1.y,u1.x), prmh(u1.w,u1.z)}; qh[0] = t.b;
    t.u = (uint4){prml(u0.y,u0.x), prml(u0.w,u0.z), prml(u1.y,u1.x), prml(u1.w,u1.z)}; ql[0] = t.b;
    t.u = (uint4){prmh(u2.y,u2.x), prmh(u2.w,u2.z), prmh(u3.y,u3.x), prmh(u3.w,u3.z)}; qh[1] = t.b;
    t.u = (uint4){prml(u2.y,u2.x), prml(u2.w,u2.z), prml(u3.y,u3.x), prml(u3.w,u3.z)}; ql[1] = t.b;
  }

  f32x4 o[4];
  #pragma unroll
  for (int i = 0; i < 4; ++i) o[i] = (f32x4){0.f,0.f,0.f,0.f};
  float m = -INFINITY, lpart = 0.f;

  const int rr0 = tid >> 3, ci = tid & 7;         // 64 rows x 8 chunks

  uint4 k0, vr0;
  #define ISSUE_FL(KC) do{ \
    k0  = *(const uint4*)(Kb + ((size_t)bh*SS + (KC)*64 + rr0)*DKH + ci*8); \
    vr0 = *(const uint4*)(Vt + ((size_t)bh*DKH + rr0)*SS + (KC)*64 + ci*8); \
  }while(0)

  ISSUE_FL(0);
  *(uint4*)&Khs[swz8(rr0, ci)] = k0;
  *(uint4*)&Vts[swz8(rr0, ci)] = vr0;
  __syncthreads();                                 // staging + tshare visible
  const float tsc2 = tshare;

  for (int kc = 0; kc < 16; ++kc){
    if (kc){
      *(uint4*)&Khs[swz8(rr0, ci)] = k0;
      *(uint4*)&Vts[swz8(rr0, ci)] = vr0;
      __syncthreads();
    }
    if (kc < 15) ISSUE_FL(kc + 1);

    f32x4 sa[4];
    #pragma unroll
    for (int fn = 0; fn < 4; ++fn) sa[fn] = (f32x4){0.f,0.f,0.f,0.f};
    __builtin_amdgcn_s_setprio(1);
    #pragma unroll
    for (int fn = 0; fn < 4; ++fn){
      #pragma unroll
      for (int ds = 0; ds < 2; ++ds){
        bf8_t ah = *(const bf8_t*)&Khs[swz8(16*fn + c, g + 4*ds)];
        sa[fn] = MFMA16(ah, qh[ds], sa[fn]);   // 2-term: Kh . (Qh + Ql)
        sa[fn] = MFMA16(ah, ql[ds], sa[fn]);
      }
    }
    __builtin_amdgcn_s_setprio(0);

    // lane-local max over own 16 kv; shuffles only in the rare rescale path
    float pmaxr = -1e30f;
    #pragma unroll
    for (int fn = 0; fn < 4; ++fn)
      #pragma unroll
      for (int r = 0; r < 4; ++r) pmaxr = fmaxf(pmaxr, sa[fn][r]);

    if (!__all(pmaxr * tsc2 <= m + 30.f)){     // fires ~once (kc=0)
      pmaxr = fmaxf(pmaxr, __shfl_xor(pmaxr, 16, 64));
      pmaxr = fmaxf(pmaxr, __shfl_xor(pmaxr, 32, 64));
      float pmax = pmaxr * tsc2;
      float mn = fmaxf(m, pmax);
      float sc = exp2f(m - mn);
      m = mn;
      lpart *= sc;
      #pragma unroll
      for (int r = 0; r < 4; ++r){
        float so = __shfl(sc, 4*g + r, 16);    // sc of q-row 4g+r (c'=4g+r)
        #pragma unroll
        for (int fn = 0; fn < 4; ++fn) o[fn][r] *= so;
      }
    }

    const float mneg = -m;
    #pragma unroll
    for (int fn = 0; fn < 4; ++fn){
      float e0 = exp2f(fmaf(sa[fn][0], tsc2, mneg));
      float e1 = exp2f(fmaf(sa[fn][1], tsc2, mneg));
      float e2 = exp2f(fmaf(sa[fn][2], tsc2, mneg));
      float e3 = exp2f(fmaf(sa[fn][3], tsc2, mneg));
      lpart += (e0 + e1) + (e2 + e3);
      uint2 pk;
      pk.x = pk2(e0, e1);
      pk.y = pk2(e2, e3);
      const int q4 = 4*fn + g;
      const int addr = (16*w + c)*64 + ((((q4 >> 1) ^ (c & 7)) << 3)) + (q4 & 1)*4;
      *(uint2*)&Ps[addr] = pk;
    }

    __builtin_amdgcn_s_setprio(1);
    #pragma unroll
    for (int kvs = 0; kvs < 2; ++kvs){
      bf8_t pa = *(const bf8_t*)&Ps[swz8(16*w + c, g + 4*kvs)];
      #pragma unroll
      for (int fn = 0; fn < 4; ++fn){
        bf8_t vb = *(const bf8_t*)&Vts[swz8(16*fn + c, g + 4*kvs)];
        o[fn] = MFMA16(pa, vb, o[fn]);
      }
    }
    __builtin_amdgcn_s_setprio(0);
    __syncthreads();
  }
  #undef ISSUE_FL

  lpart += __shfl_xor(lpart, 16, 64);
  lpart += __shfl_xor(lpart, 32, 64);
  const int b = bh >> 4, hd = bh & 15;
  #pragma unroll
  for (int r = 0; r < 4; ++r){
    float linv = 1.f / __shfl(lpart, 4*g + r, 16);   // l of q-row 4g+r
    const int q = q0 + 16*w + 4*g + r;
    #pragma unroll
    for (int fn = 0; fn < 4; ++fn)
      aout[((size_t)(b*SS + q))*DM + hd*DKH + 16*fn + c] = f2bf(o[fn][r] * linv);
  }
}

extern "C" void kernel_launch(void* const* d_in, const int* in_sizes, int n_in,
                              void* d_out, int out_size, void* d_ws, size_t ws_size,
                              hipStream_t stream)
{
  const float* query = (const float*)d_in[0];
  const float* key   = (const float*)d_in[1];
  const float* value = (const float*)d_in[2];
  const float* Wq = (const float*)d_in[3];
  const float* bq = (const float*)d_in[4];
  const float* Wk = (const float*)d_in[5];
  const float* bk = (const float*)d_in[6];
  const float* Wv = (const float*)d_in[7];
  const float* bv = (const float*)d_in[8];
  const float* Wo = (const float*)d_in[9];
  const float* bo = (const float*)d_in[10];
  const float* Wt1 = (const float*)d_in[11];
  const float* bt1 = (const float*)d_in[12];
  const float* Wt2 = (const float*)d_in[13];
  const float* bt2 = (const float*)d_in[14];

  const size_t E = (size_t)NB*SS*DM;       // 4,194,304
  const size_t WE = (size_t)DM*DM;

  uint32* Qi  = (uint32*)d_ws;             // E uint32 (hi|lo interleaved)
  ush* Kbb = (ush*)(Qi + E);               // E ush (plain bf16)
  ush* Vtb = Kbb + E;                      // E ush (b*16+h, dk, s)
  ush* Aob = Vtb + E;                      // E ush  -- also aliased as xqb
  ush* xqb = Aob;                          // alias: consumed before Aob written
  ush* xkb = Aob + E;
  ush* xvb = xkb + E;
  ush* Wqh = xvb + E;
  ush* Wkh = Wqh + WE;
  ush* Wvh = Wkh + WE;
  ush* Woh = Wvh + WE;
  float* stats = (float*)(Woh + WE);       // 256 floats

  hipMemsetAsync(stats, 0, 4*NBH*sizeof(float), stream);

  xconv<<<dim3(2048, 3), 256, 0, stream>>>(query, key, value, xqb, xkb, xvb);

  dim3 wb(32, 8), wg(32, 32, 4);
  wconv4<<<wg, wb, 0, stream>>>(Wq, Wk, Wv, Wo, Wqh, Wkh, Wvh, Woh);

  proj_qkv<<<768, 256, 0, stream>>>(xqb, xkb, xvb,
      Wqh, Wkh, Wvh, bq, bk, bv, Qi, Kbb, Vtb);

  attn_stats_mfma<<<512, 512, 0, stream>>>(Qi, Kbb, stats);
  attn_flash_mfma<<<512, 512, 0, stream>>>(Qi, Kbb, Vtb, stats,
      Wt1, bt1, Wt2, bt2, Aob);

  gemm_out<<<512, 256, 0, stream>>>(Aob, Woh, bo, (float*)d_out);
}

// Round 19
// 145.055 us; speedup vs baseline: 1.1369x; 1.0272x over previous
//
#include <hip/hip_runtime.h>
#include <hip/hip_bf16.h>
#include <math.h>

#define SS   1024
#define DM   1024
#define NH   16
#define DKH  64
#define NB   4
#define NBH  64

typedef unsigned short ush;
typedef unsigned int uint32;
typedef __attribute__((ext_vector_type(8))) short bf8_t;   // 8 bf16 = 4 VGPR
typedef __attribute__((ext_vector_type(4))) float f32x4;
#define MFMA16(a,b,c) __builtin_amdgcn_mfma_f32_16x16x32_bf16((a),(b),(c),0,0,0)

__device__ __forceinline__ ush f2bf(float x){ return __bfloat16_as_ushort(__float2bfloat16(x)); }
__device__ __forceinline__ float bf2f(ush h){ return __bfloat162float(__ushort_as_bfloat16(h)); }
__device__ __forceinline__ uint32 pk2(float a, float b){
  return (uint32)f2bf(a) | ((uint32)f2bf(b) << 16);
}
// pack value as (lo16<<16)|hi16
__device__ __forceinline__ uint32 pkhl(float v){
  ush h = f2bf(v);
  return (uint32)h | ((uint32)f2bf(v - bf2f(h)) << 16);
}
// extract hi/lo bf16 pairs from two interleaved uints (ulo = smaller d)
__device__ __forceinline__ uint32 prmh(uint32 uhi, uint32 ulo){
  return __builtin_amdgcn_perm(uhi, ulo, 0x05040100u);
}
__device__ __forceinline__ uint32 prml(uint32 uhi, uint32 ulo){
  return __builtin_amdgcn_perm(uhi, ulo, 0x07060302u);
}
// [rows][64]-ush tile, XOR swizzle on 16B chunks
__device__ __forceinline__ int swz8(int row, int chunk){
  return row*64 + (((chunk) ^ (row & 7)) << 3);
}
union U4B8 { uint4 u; bf8_t b; };

// ---- x fp32 -> bf16 (hi only)
__global__ __launch_bounds__(256) void xconv(
    const float* __restrict__ q, const float* __restrict__ k, const float* __restrict__ v,
    ush* __restrict__ xq, ush* __restrict__ xk, ush* __restrict__ xv)
{
  const float* src = (blockIdx.y==0)?q:(blockIdx.y==1)?k:v;
  ush* dst = (blockIdx.y==0)?xq:(blockIdx.y==1)?xk:xv;
  const size_t i = ((size_t)blockIdx.x*256 + threadIdx.x)*8;
  float4 a = *(const float4*)&src[i];
  float4 b = *(const float4*)&src[i+4];
  uint4 o;
  o.x = pk2(a.x, a.y); o.y = pk2(a.z, a.w);
  o.z = pk2(b.x, b.y); o.w = pk2(b.z, b.w);
  *(uint4*)&dst[i] = o;
}

// ---- weight convert: W (K x N) fp32 -> Wt (N x K) bf16 hi only
__global__ void wconv4(const float* __restrict__ W0, const float* __restrict__ W1,
                       const float* __restrict__ W2, const float* __restrict__ W3,
                       ush* __restrict__ H0, ush* __restrict__ H1,
                       ush* __restrict__ H2, ush* __restrict__ H3)
{
  __shared__ float T[32][33];
  const int tx = threadIdx.x, ty = threadIdx.y;    // (32,8)
  const int z = blockIdx.z;
  const float* W = (z==0)?W0:(z==1)?W1:(z==2)?W2:W3;
  ush* H = (z==0)?H0:(z==1)?H1:(z==2)?H2:H3;
  const int k0 = blockIdx.y*32, n0 = blockIdx.x*32;
  #pragma unroll
  for (int i = 0; i < 4; ++i){
    int r = ty + 8*i;
    T[r][tx] = W[(size_t)(k0 + r)*DM + n0 + tx];
  }
  __syncthreads();
  #pragma unroll
  for (int i = 0; i < 4; ++i){
    int r = ty + 8*i;              // n-local
    H[(size_t)(n0 + r)*DM + k0 + tx] = f2bf(T[tx][r]);
  }
}

// ---- fused Q/K/V projection: BK=32, 1-term (W hi), double-buffered LDS via
// global_load_lds width-16 with pre-swizzled per-lane SOURCE addresses.
__global__ __launch_bounds__(256) void proj_qkv(
    const ush* __restrict__ xq, const ush* __restrict__ xk, const ush* __restrict__ xv,
    const ush* __restrict__ Wqh, const ush* __restrict__ Wkh, const ush* __restrict__ Wvh,
    const float* __restrict__ bq, const float* __restrict__ bk,
    const float* __restrict__ bv,
    uint32* __restrict__ Qi, ush* __restrict__ Kb, ush* __restrict__ Vt)
{
  // staging: 2 buffers x (As 4096 | Bhs 4096) = 32 KB; V-epilogue 4*4224 ush
  __shared__ ush SMEM[16896];

  const int fid = blockIdx.x;
  const int glob = (fid & 7)*96 + (fid >> 3);  // XCD-contiguous chunks of 96
  const int z = glob >> 8, rem = glob & 255;
  const int m0 = (rem >> 3) * 128, n0 = (rem & 7) * 128;

  const ush* A  = (z==0) ? xq  : (z==1) ? xk  : xv;
  const ush* Bh = (z==0) ? Wqh : (z==1) ? Wkh : Wvh;

  const int tid = threadIdx.x;
  const int lane = tid & 63, w = tid >> 6;
  const int c = lane & 15, g = lane >> 4;
  const int wr = w >> 1, wc = w & 1;

  f32x4 acc[4][4];
  #pragma unroll
  for (int i = 0; i < 4; ++i)
    #pragma unroll
    for (int j = 0; j < 4; ++j) acc[i][j] = (f32x4){0.f,0.f,0.f,0.f};

  const int prow0 = w*16 + (lane >> 3), prow1 = prow0 + 8;
  const int jj = lane & 7;
  const int sg0 = jj ^ (prow0 & 7), sg1 = jj ^ (prow1 & 7);
  const size_t aoff0 = (size_t)(2*prow0 + (sg0 >> 2))*DM + (sg0 & 3)*8;
  const size_t aoff1 = (size_t)(2*prow1 + (sg1 >> 2))*DM + (sg1 & 3)*8;
  const ush* Aab = A  + (size_t)m0*DM;
  const ush* Bhb = Bh + (size_t)n0*DM;
  const int lb0 = w*1024, lb1 = w*1024 + 512;   // wave-uniform LDS bases (ush)

#define GLL(GP, LIDX) __builtin_amdgcn_global_load_lds( \
    (const __attribute__((address_space(1))) unsigned int*)(GP), \
    (__attribute__((address_space(3))) unsigned int*)(&SMEM[LIDX]), 16, 0, 0)

#define ISSUE_PROJ(BUFO, KT) do{ \
    GLL(Aab + aoff0 + (KT), (BUFO) + lb0); \
    GLL(Aab + aoff1 + (KT), (BUFO) + lb1); \
    GLL(Bhb + aoff0 + (KT), (BUFO) + 4096 + lb0); \
    GLL(Bhb + aoff1 + (KT), (BUFO) + 4096 + lb1); \
  }while(0)

  const int csw = (((4*(c & 1) + g) ^ ((c >> 1) & 7)) << 3);

  ISSUE_PROJ(0, 0);
  int cur = 0;
  for (int kt = 0; kt < DM; kt += 32){
    __syncthreads();                       // drains vmcnt -> buf[cur] ready
    if (kt + 32 < DM) ISSUE_PROJ((cur ^ 1)*8192, kt + 32);

    const ush* As  = SMEM + cur*8192;
    const ush* Bhs = As + 4096;

    bf8_t a_h[4];
    #pragma unroll
    for (int fm = 0; fm < 4; ++fm)
      a_h[fm] = *(const bf8_t*)&As[(32*wr + 8*fm + (c>>1))*64 + csw];
    __builtin_amdgcn_s_setprio(1);
    #pragma unroll
    for (int fn = 0; fn < 4; ++fn){
      bf8_t b_h = *(const bf8_t*)&Bhs[(32*wc + 8*fn + (c>>1))*64 + csw];
      #pragma unroll
      for (int fm = 0; fm < 4; ++fm)
        acc[fm][fn] = MFMA16(a_h[fm], b_h, acc[fm][fn]);
    }
    __builtin_amdgcn_s_setprio(0);
    cur ^= 1;
  }
#undef ISSUE_PROJ
#undef GLL

  if (z == 0){
    #pragma unroll
    for (int fm = 0; fm < 4; ++fm){
      #pragma unroll
      for (int fn = 0; fn < 4; ++fn){
        const int col = n0 + 64*wc + 16*fn + c;
        const float bb = bq[col];
        const int row0 = m0 + 64*wr + 16*fm + 4*g;
        const int hd = col >> 6, d = col & 63;
        #pragma unroll
        for (int r = 0; r < 4; ++r){
          const int row = row0 + r;
          const int b = row >> 10, s = row & 1023;
          Qi[((size_t)(b*NH + hd)*SS + s)*DKH + d] = pkhl(acc[fm][fn][r] + bb);
        }
      }
    }
  } else if (z == 1){
    #pragma unroll
    for (int fm = 0; fm < 4; ++fm){
      #pragma unroll
      for (int fn = 0; fn < 4; ++fn){
        const int col = n0 + 64*wc + 16*fn + c;
        const float bb = bk[col];
        const int row0 = m0 + 64*wr + 16*fm + 4*g;
        const int hd = col >> 6, d = col & 63;
        #pragma unroll
        for (int r = 0; r < 4; ++r){
          const int row = row0 + r;
          const int b = row >> 10, s = row & 1023;
          Kb[((size_t)(b*NH + hd)*SS + s)*DKH + d] = f2bf(acc[fm][fn][r] + bb);
        }
      }
    }
  } else {
    // V: transpose wave's 64(s) x 64(d) sub-tile through LDS -> coalesced (d,s)
    __syncthreads();                      // all waves done reading staging LDS
    ush* Vep = SMEM + w*4224;             // 64 rows(d) x 66 cols(s)
    #pragma unroll
    for (int fm = 0; fm < 4; ++fm){
      #pragma unroll
      for (int fn = 0; fn < 4; ++fn){
        const float bb = bv[n0 + 64*wc + 16*fn + c];
        #pragma unroll
        for (int r = 0; r < 4; ++r)
          Vep[(16*fn + c)*66 + 16*fm + 4*g + r] = f2bf(acc[fm][fn][r] + bb);
      }
    }
    const int b = m0 >> 10;
    const int s0 = (m0 & 1023) + 64*wr;
    const int hd = (n0 >> 6) + wc;
    const size_t vbase = ((size_t)(b*NH + hd))*DKH*SS;
    #pragma unroll
    for (int it = 0; it < 8; ++it){
      const int dr = 8*it + (lane >> 3);
      const int sc = (lane & 7)*8;
      uint4 vv = *(const uint4*)&Vep[dr*66 + sc];
      *(uint4*)&Vt[vbase + (size_t)dr*SS + s0 + sc] = vv;
    }
  }
}

// ---- output projection: C = A(bf16) @ Wo^T + bo, 128x64 tile, paired-row LDS
__global__ __launch_bounds__(256) void gemm_out(
    const ush* __restrict__ Abf, const ush* __restrict__ Bth,
    const float* __restrict__ bias, float* __restrict__ outf)
{
  __shared__ ush As[4096], Bs[2048];

  const int fid = blockIdx.x;
  const int glob = (fid & 7)*64 + (fid >> 3);
  const int m0 = (glob >> 4)*128, n0 = (glob & 15)*64;

  const int tid = threadIdx.x;
  const int lane = tid & 63, w = tid >> 6;
  const int c = lane & 15, g = lane >> 4;
  const int wr = w >> 1, wc = w & 1;

  f32x4 acc[4][2];
  #pragma unroll
  for (int i = 0; i < 4; ++i){ acc[i][0] = (f32x4){0,0,0,0}; acc[i][1] = (f32x4){0,0,0,0}; }

  const int prow = tid >> 3, ci = tid & 7;
  const int lr   = 2*prow + (ci >> 2);
  const int koff = (ci & 3) << 3;
  const int ws0  = prow*64 + ((ci ^ (prow & 7)) << 3);
  const int ws1  = ws0 + 32*64;
  const int csw  = (((4*(c & 1) + g) ^ ((c >> 1) & 7)) << 3);

  uint4 ar0, ar1, brr;
  #define ISSUE_OUT(KT) do{ \
    ar0 = *(const uint4*)(Abf + (size_t)(m0 + lr)*DM + (KT) + koff); \
    ar1 = *(const uint4*)(Abf + (size_t)(m0 + lr + 64)*DM + (KT) + koff); \
    brr = *(const uint4*)(Bth + (size_t)(n0 + lr)*DM + (KT) + koff); \
  }while(0)

  ISSUE_OUT(0);
  for (int kt = 0; kt < DM; kt += 32){
    *(uint4*)&As[ws0] = ar0;
    *(uint4*)&As[ws1] = ar1;
    if (lr < 64) *(uint4*)&Bs[ws0] = brr;
    __syncthreads();
    if (kt + 32 < DM) ISSUE_OUT(kt + 32);

    bf8_t a_h[4];
    #pragma unroll
    for (int fm = 0; fm < 4; ++fm)
      a_h[fm] = *(const bf8_t*)&As[(32*wr + 8*fm + (c>>1))*64 + csw];
    #pragma unroll
    for (int fn = 0; fn < 2; ++fn){
      bf8_t b_h = *(const bf8_t*)&Bs[(16*wc + 8*fn + (c>>1))*64 + csw];
      #pragma unroll
      for (int fm = 0; fm < 4; ++fm)
        acc[fm][fn] = MFMA16(a_h[fm], b_h, acc[fm][fn]);
    }
    __syncthreads();
  }
  #undef ISSUE_OUT

  #pragma unroll
  for (int fm = 0; fm < 4; ++fm){
    #pragma unroll
    for (int fn = 0; fn < 2; ++fn){
      const int col = n0 + 32*wc + 16*fn + c;
      const float bb = bias[col];
      const int row0 = m0 + 64*wr + 16*fm + 4*g;
      #pragma unroll
      for (int r = 0; r < 4; ++r)
        outf[(size_t)(row0 + r)*DM + col] = acc[fm][fn][r] + bb;
    }
  }
}

// ---- Stats pass: QBLK=128 (512 thr, 8 waves), KVBLK=64, 1-term QK (Qh),
// plain-bf16 K staging, prefetch. Atomic partial sums only (no election).
__global__ __launch_bounds__(512) void attn_stats_mfma(
    const uint32* __restrict__ Qi, const ush* __restrict__ Kb,
    float* __restrict__ stats)
{
  __shared__ ush Khs[64*64];
  __shared__ float red[8][3];
  const int tid = threadIdx.x, lane = tid & 63, w = tid >> 6;   // w 0..7
  const int c = lane & 15, g = lane >> 4;
  const int fid = blockIdx.x;
  const int glob = (fid & 7)*64 + (fid >> 3);     // 512 blocks, XCD-chunked
  const int bh = glob >> 3, q0 = (glob & 7)*128;

  bf8_t qh[2];
  {
    const size_t qoff = ((size_t)bh*SS + q0 + 16*w + c)*DKH + 8*g;
    uint4 u0 = *(const uint4*)(Qi + qoff);
    uint4 u1 = *(const uint4*)(Qi + qoff + 4);
    uint4 u2 = *(const uint4*)(Qi + qoff + 32);
    uint4 u3 = *(const uint4*)(Qi + qoff + 36);
    U4B8 t;
    t.u = (uint4){prmh(u0.y,u0.x), prmh(u0.w,u0.z), prmh(u1.y,u1.x), prmh(u1.w,u1.z)}; qh[0] = t.b;
    t.u = (uint4){prmh(u2.y,u2.x), prmh(u2.w,u2.z), prmh(u3.y,u3.x), prmh(u3.w,u3.z)}; qh[1] = t.b;
  }

  float ssum = 0.f, rmax = -1e30f, lsum = 0.f, l2sum = 0.f;
  const int rr0 = tid >> 3, ci = tid & 7;         // 64 rows x 8 chunks

  uint4 k0;
  #define ISSUE_ST(KC) do{ \
    k0 = *(const uint4*)(Kb + ((size_t)bh*SS + (KC)*64 + rr0)*DKH + ci*8); \
  }while(0)

  ISSUE_ST(0);
  for (int kc = 0; kc < 16; ++kc){
    *(uint4*)&Khs[swz8(rr0, ci)] = k0;
    __syncthreads();
    if (kc < 15) ISSUE_ST(kc + 1);

    f32x4 sa[4];
    #pragma unroll
    for (int fn = 0; fn < 4; ++fn) sa[fn] = (f32x4){0.f,0.f,0.f,0.f};
    __builtin_amdgcn_s_setprio(1);
    #pragma unroll
    for (int fn = 0; fn < 4; ++fn){
      #pragma unroll
      for (int ds = 0; ds < 2; ++ds){
        bf8_t ah = *(const bf8_t*)&Khs[swz8(16*fn + c, g + 4*ds)];
        sa[fn] = MFMA16(ah, qh[ds], sa[fn]);      // 1-term: Kh . Qh
      }
    }
    __builtin_amdgcn_s_setprio(0);
    #pragma unroll
    for (int fn = 0; fn < 4; ++fn){
      #pragma unroll
      for (int r = 0; r < 4; ++r){
        float s = sa[fn][r] * 0.125f;
        ssum += s;
        rmax = fmaxf(rmax, s);
        float e = exp2f(s * 0.7213475204f);       // exp(s/2); |s|<50 fp32-safe
        lsum += e;
        l2sum = fmaf(e, e, l2sum);
      }
    }
    __syncthreads();
  }
  #undef ISSUE_ST

  rmax  = fmaxf(rmax, __shfl_xor(rmax, 16, 64));
  rmax  = fmaxf(rmax, __shfl_xor(rmax, 32, 64));
  lsum  += __shfl_xor(lsum, 16, 64);   lsum  += __shfl_xor(lsum, 32, 64);
  l2sum += __shfl_xor(l2sum, 16, 64);  l2sum += __shfl_xor(l2sum, 32, 64);
  float varc = (l2sum/(lsum*lsum) - (1.0f/1024.f)) * (1.0f/1023.f);
  float a0 = ssum, a1 = rmax * 0.25f, a2 = varc * 0.25f;
  #pragma unroll
  for (int off = 1; off < 64; off <<= 1){
    a0 += __shfl_xor(a0, off, 64);
    a1 += __shfl_xor(a1, off, 64);
    a2 += __shfl_xor(a2, off, 64);
  }
  if (lane == 0){ red[w][0] = a0; red[w][1] = a1; red[w][2] = a2; }
  __syncthreads();
  if (tid == 0){
    float r0 = 0.f, r1 = 0.f, r2 = 0.f;
    #pragma unroll
    for (int i = 0; i < 8; ++i){ r0 += red[i][0]; r1 += red[i][1]; r2 += red[i][2]; }
    atomicAdd(&stats[bh*4+0], r0);
    atomicAdd(&stats[bh*4+1], r1);
    atomicAdd(&stats[bh*4+2], r2);
  }
}

// ---- Flash pass: QBLK=128 (512 thr), KVBLK=64 (16 iters), swapped QK^T
// 1-term (Kh . Qh), plain-bf16 K, exp2, defer-max, swizzled LDS, prefetch.
// LDS = 32 KB. Time-MLP in prologue, lane-parallel + LDS broadcast.
__global__ __launch_bounds__(512) void attn_flash_mfma(
    const uint32* __restrict__ Qi, const ush* __restrict__ Kb,
    const ush* __restrict__ Vt, const float* __restrict__ stats,
    const float* __restrict__ Wt1, const float* __restrict__ bt1,
    const float* __restrict__ Wt2, const float* __restrict__ bt2,
    ush* __restrict__ aout)
{
  __shared__ ush Khs[64*64], Vts[64*64], Ps[128*64];
  __shared__ float tshare;
  const int tid = threadIdx.x, lane = tid & 63, w = tid >> 6;   // w 0..7
  const int c = lane & 15, g = lane >> 4;
  const int fid = blockIdx.x;
  const int glob = (fid & 7)*64 + (fid >> 3);     // 512 blocks, XCD-chunked
  const int bh = glob >> 3, q0 = (glob & 7)*128;

  // ---- lane-parallel time-MLP: lane j of wave 0 computes hidden unit j
  if (tid < 16){
    float mean = fminf(fmaxf(stats[bh*4+0] * (1.f/(1024.f*1024.f)), -10.f), 10.f);
    float mx   = fminf(fmaxf(stats[bh*4+1] * (1.f/1024.f), -10.f), 10.f);
    float ent  = fminf(fmaxf(stats[bh*4+2] * (1.f/1024.f),   0.f),  1.f);
    float h = tanhf(mean*Wt1[tid] + mx*Wt1[16+tid] + ent*Wt1[32+tid] + bt1[tid])
              * Wt2[tid];
    h += __shfl_xor(h, 1, 64);
    h += __shfl_xor(h, 2, 64);
    h += __shfl_xor(h, 4, 64);
    h += __shfl_xor(h, 8, 64);
    if (tid == 0){
      float raw = h + bt2[0];
      float sig = 1.f / (1.f + expf(-raw));
      float t = 0.01f + sig * 1.99f;
      t = fminf(fminf(fmaxf(t, 0.01f), 2.0f), 0.85f);
      tshare = (0.5f / t) * 1.44269504f;          // exp2 domain
    }
  }

  bf8_t qh[2];
  {
    const size_t qoff = ((size_t)bh*SS + q0 + 16*w + c)*DKH + 8*g;
    uint4 u0 = *(const uint4*)(Qi + qoff);
    uint4 u1 = *(const uint4*)(Qi + qoff + 4);
    uint4 u2 = *(const uint4*)(Qi + qoff + 32);
    uint4 u3 = *(const uint4*)(Qi + qoff + 36);
    U4B8 t;
    t.u = (uint4){prmh(u0.y,u0.x), prmh(u0.w,u0.z), prmh(u1.y,u1.x), prmh(u1.w,u1.z)}; qh[0] = t.b;
    t.u = (uint4){prmh(u2.y,u2.x), prmh(u2.w,u2.z), prmh(u3.y,u3.x), prmh(u3.w,u3.z)}; qh[1] = t.b;
  }

  f32x4 o[4];
  #pragma unroll
  for (int i = 0; i < 4; ++i) o[i] = (f32x4){0.f,0.f,0.f,0.f};
  float m = -INFINITY, lpart = 0.f;

  const int rr0 = tid >> 3, ci = tid & 7;         // 64 rows x 8 chunks

  uint4 k0, vr0;
  #define ISSUE_FL(KC) do{ \
    k0  = *(const uint4*)(Kb + ((size_t)bh*SS + (KC)*64 + rr0)*DKH + ci*8); \
    vr0 = *(const uint4*)(Vt + ((size_t)bh*DKH + rr0)*SS + (KC)*64 + ci*8); \
  }while(0)

  ISSUE_FL(0);
  *(uint4*)&Khs[swz8(rr0, ci)] = k0;
  *(uint4*)&Vts[swz8(rr0, ci)] = vr0;
  __syncthreads();                                 // staging + tshare visible
  const float tsc2 = tshare;

  for (int kc = 0; kc < 16; ++kc){
    if (kc){
      *(uint4*)&Khs[swz8(rr0, ci)] = k0;
      *(uint4*)&Vts[swz8(rr0, ci)] = vr0;
      __syncthreads();
    }
    if (kc < 15) ISSUE_FL(kc + 1);

    f32x4 sa[4];
    #pragma unroll
    for (int fn = 0; fn < 4; ++fn) sa[fn] = (f32x4){0.f,0.f,0.f,0.f};
    __builtin_amdgcn_s_setprio(1);
    #pragma unroll
    for (int fn = 0; fn < 4; ++fn){
      #pragma unroll
      for (int ds = 0; ds < 2; ++ds){
        bf8_t ah = *(const bf8_t*)&Khs[swz8(16*fn + c, g + 4*ds)];
        sa[fn] = MFMA16(ah, qh[ds], sa[fn]);   // 1-term: Kh . Qh
      }
    }
    __builtin_amdgcn_s_setprio(0);

    // lane-local max over own 16 kv; shuffles only in the rare rescale path
    float pmaxr = -1e30f;
    #pragma unroll
    for (int fn = 0; fn < 4; ++fn)
      #pragma unroll
      for (int r = 0; r < 4; ++r) pmaxr = fmaxf(pmaxr, sa[fn][r]);

    if (!__all(pmaxr * tsc2 <= m + 30.f)){     // fires ~once (kc=0)
      pmaxr = fmaxf(pmaxr, __shfl_xor(pmaxr, 16, 64));
      pmaxr = fmaxf(pmaxr, __shfl_xor(pmaxr, 32, 64));
      float pmax = pmaxr * tsc2;
      float mn = fmaxf(m, pmax);
      float sc = exp2f(m - mn);
      m = mn;
      lpart *= sc;
      #pragma unroll
      for (int r = 0; r < 4; ++r){
        float so = __shfl(sc, 4*g + r, 16);    // sc of q-row 4g+r (c'=4g+r)
        #pragma unroll
        for (int fn = 0; fn < 4; ++fn) o[fn][r] *= so;
      }
    }

    const float mneg = -m;
    #pragma unroll
    for (int fn = 0; fn < 4; ++fn){
      float e0 = exp2f(fmaf(sa[fn][0], tsc2, mneg));
      float e1 = exp2f(fmaf(sa[fn][1], tsc2, mneg));
      float e2 = exp2f(fmaf(sa[fn][2], tsc2, mneg));
      float e3 = exp2f(fmaf(sa[fn][3], tsc2, mneg));
      lpart += (e0 + e1) + (e2 + e3);
      uint2 pk;
      pk.x = pk2(e0, e1);
      pk.y = pk2(e2, e3);
      const int q4 = 4*fn + g;
      const int addr = (16*w + c)*64 + ((((q4 >> 1) ^ (c & 7)) << 3)) + (q4 & 1)*4;
      *(uint2*)&Ps[addr] = pk;
    }

    __builtin_amdgcn_s_setprio(1);
    #pragma unroll
    for (int kvs = 0; kvs < 2; ++kvs){
      bf8_t pa = *(const bf8_t*)&Ps[swz8(16*w + c, g + 4*kvs)];
      #pragma unroll
      for (int fn = 0; fn < 4; ++fn){
        bf8_t vb = *(const bf8_t*)&Vts[swz8(16*fn + c, g + 4*kvs)];
        o[fn] = MFMA16(pa, vb, o[fn]);
      }
    }
    __builtin_amdgcn_s_setprio(0);
    __syncthreads();
  }
  #undef ISSUE_FL

  lpart += __shfl_xor(lpart, 16, 64);
  lpart += __shfl_xor(lpart, 32, 64);
  const int b = bh >> 4, hd = bh & 15;
  #pragma unroll
  for (int r = 0; r < 4; ++r){
    float linv = 1.f / __shfl(lpart, 4*g + r, 16);   // l of q-row 4g+r
    const int q = q0 + 16*w + 4*g + r;
    #pragma unroll
    for (int fn = 0; fn < 4; ++fn)
      aout[((size_t)(b*SS + q))*DM + hd*DKH + 16*fn + c] = f2bf(o[fn][r] * linv);
  }
}

extern "C" void kernel_launch(void* const* d_in, const int* in_sizes, int n_in,
                              void* d_out, int out_size, void* d_ws, size_t ws_size,
                              hipStream_t stream)
{
  const float* query = (const float*)d_in[0];
  const float* key   = (const float*)d_in[1];
  const float* value = (const float*)d_in[2];
  const float* Wq = (const float*)d_in[3];
  const float* bq = (const float*)d_in[4];
  const float* Wk = (const float*)d_in[5];
  const float* bk = (const float*)d_in[6];
  const float* Wv = (const float*)d_in[7];
  const float* bv = (const float*)d_in[8];
  const float* Wo = (const float*)d_in[9];
  const float* bo = (const float*)d_in[10];
  const float* Wt1 = (const float*)d_in[11];
  const float* bt1 = (const float*)d_in[12];
  const float* Wt2 = (const float*)d_in[13];
  const float* bt2 = (const float*)d_in[14];

  const size_t E = (size_t)NB*SS*DM;       // 4,194,304
  const size_t WE = (size_t)DM*DM;

  uint32* Qi  = (uint32*)d_ws;             // E uint32 (hi|lo interleaved)
  ush* Kbb = (ush*)(Qi + E);               // E ush (plain bf16)
  ush* Vtb = Kbb + E;                      // E ush (b*16+h, dk, s)
  ush* Aob = Vtb + E;                      // E ush  -- also aliased as xqb
  ush* xqb = Aob;                          // alias: consumed before Aob written
  ush* xkb = Aob + E;
  ush* xvb = xkb + E;
  ush* Wqh = xvb + E;
  ush* Wkh = Wqh + WE;
  ush* Wvh = Wkh + WE;
  ush* Woh = Wvh + WE;
  float* stats = (float*)(Woh + WE);       // 256 floats

  hipMemsetAsync(stats, 0, 4*NBH*sizeof(float), stream);

  xconv<<<dim3(2048, 3), 256, 0, stream>>>(query, key, value, xqb, xkb, xvb);

  dim3 wb(32, 8), wg(32, 32, 4);
  wconv4<<<wg, wb, 0, stream>>>(Wq, Wk, Wv, Wo, Wqh, Wkh, Wvh, Woh);

  proj_qkv<<<768, 256, 0, stream>>>(xqb, xkb, xvb,
      Wqh, Wkh, Wvh, bq, bk, bv, Qi, Kbb, Vtb);

  attn_stats_mfma<<<512, 512, 0, stream>>>(Qi, Kbb, stats);
  attn_flash_mfma<<<512, 512, 0, stream>>>(Qi, Kbb, Vtb, stats,
      Wt1, bt1, Wt2, bt2, Aob);

  gemm_out<<<512, 256, 0, stream>>>(Aob, Woh, bo, (float*)d_out);
}

// Round 20
// 144.557 us; speedup vs baseline: 1.1409x; 1.0034x over previous
//
#include <hip/hip_runtime.h>
#include <hip/hip_bf16.h>
#include <math.h>

#define SS   1024
#define DM   1024
#define NH   16
#define DKH  64
#define NB   4
#define NBH  64

typedef unsigned short ush;
typedef unsigned int uint32;
typedef __attribute__((ext_vector_type(8))) short bf8_t;   // 8 bf16 = 4 VGPR
typedef __attribute__((ext_vector_type(4))) float f32x4;
#define MFMA16(a,b,c) __builtin_amdgcn_mfma_f32_16x16x32_bf16((a),(b),(c),0,0,0)

__device__ __forceinline__ ush f2bf(float x){ return __bfloat16_as_ushort(__float2bfloat16(x)); }
__device__ __forceinline__ uint32 pk2(float a, float b){
  return (uint32)f2bf(a) | ((uint32)f2bf(b) << 16);
}
// [rows][64]-ush tile, XOR swizzle on 16B chunks
__device__ __forceinline__ int swz8(int row, int chunk){
  return row*64 + (((chunk) ^ (row & 7)) << 3);
}

// ---- x fp32 -> bf16 (hi only)
__global__ __launch_bounds__(256) void xconv(
    const float* __restrict__ q, const float* __restrict__ k, const float* __restrict__ v,
    ush* __restrict__ xq, ush* __restrict__ xk, ush* __restrict__ xv)
{
  const float* src = (blockIdx.y==0)?q:(blockIdx.y==1)?k:v;
  ush* dst = (blockIdx.y==0)?xq:(blockIdx.y==1)?xk:xv;
  const size_t i = ((size_t)blockIdx.x*256 + threadIdx.x)*8;
  float4 a = *(const float4*)&src[i];
  float4 b = *(const float4*)&src[i+4];
  uint4 o;
  o.x = pk2(a.x, a.y); o.y = pk2(a.z, a.w);
  o.z = pk2(b.x, b.y); o.w = pk2(b.z, b.w);
  *(uint4*)&dst[i] = o;
}

// ---- weight convert: W (K x N) fp32 -> Wt (N x K) bf16 hi only
__global__ void wconv4(const float* __restrict__ W0, const float* __restrict__ W1,
                       const float* __restrict__ W2, const float* __restrict__ W3,
                       ush* __restrict__ H0, ush* __restrict__ H1,
                       ush* __restrict__ H2, ush* __restrict__ H3)
{
  __shared__ float T[32][33];
  const int tx = threadIdx.x, ty = threadIdx.y;    // (32,8)
  const int z = blockIdx.z;
  const float* W = (z==0)?W0:(z==1)?W1:(z==2)?W2:W3;
  ush* H = (z==0)?H0:(z==1)?H1:(z==2)?H2:H3;
  const int k0 = blockIdx.y*32, n0 = blockIdx.x*32;
  #pragma unroll
  for (int i = 0; i < 4; ++i){
    int r = ty + 8*i;
    T[r][tx] = W[(size_t)(k0 + r)*DM + n0 + tx];
  }
  __syncthreads();
  #pragma unroll
  for (int i = 0; i < 4; ++i){
    int r = ty + 8*i;              // n-local
    H[(size_t)(n0 + r)*DM + k0 + tx] = f2bf(T[tx][r]);
  }
}

// ---- fused Q/K/V projection: BK=32, 1-term (W hi), double-buffered LDS via
// global_load_lds width-16 with pre-swizzled per-lane SOURCE addresses.
// Q/K out plain bf16 (b*16+h, s, dk); V out bf16 transposed (b*16+h, dk, s).
__global__ __launch_bounds__(256) void proj_qkv(
    const ush* __restrict__ xq, const ush* __restrict__ xk, const ush* __restrict__ xv,
    const ush* __restrict__ Wqh, const ush* __restrict__ Wkh, const ush* __restrict__ Wvh,
    const float* __restrict__ bq, const float* __restrict__ bk,
    const float* __restrict__ bv,
    ush* __restrict__ Qb, ush* __restrict__ Kb, ush* __restrict__ Vt)
{
  // staging: 2 buffers x (As 4096 | Bhs 4096) = 32 KB; V-epilogue 4*4224 ush
  __shared__ ush SMEM[16896];

  const int fid = blockIdx.x;
  const int glob = (fid & 7)*96 + (fid >> 3);  // XCD-contiguous chunks of 96
  const int z = glob >> 8, rem = glob & 255;
  const int m0 = (rem >> 3) * 128, n0 = (rem & 7) * 128;

  const ush* A  = (z==0) ? xq  : (z==1) ? xk  : xv;
  const ush* Bh = (z==0) ? Wqh : (z==1) ? Wkh : Wvh;

  const int tid = threadIdx.x;
  const int lane = tid & 63, w = tid >> 6;
  const int c = lane & 15, g = lane >> 4;
  const int wr = w >> 1, wc = w & 1;

  f32x4 acc[4][4];
  #pragma unroll
  for (int i = 0; i < 4; ++i)
    #pragma unroll
    for (int j = 0; j < 4; ++j) acc[i][j] = (f32x4){0.f,0.f,0.f,0.f};

  const int prow0 = w*16 + (lane >> 3), prow1 = prow0 + 8;
  const int jj = lane & 7;
  const int sg0 = jj ^ (prow0 & 7), sg1 = jj ^ (prow1 & 7);
  const size_t aoff0 = (size_t)(2*prow0 + (sg0 >> 2))*DM + (sg0 & 3)*8;
  const size_t aoff1 = (size_t)(2*prow1 + (sg1 >> 2))*DM + (sg1 & 3)*8;
  const ush* Aab = A  + (size_t)m0*DM;
  const ush* Bhb = Bh + (size_t)n0*DM;
  const int lb0 = w*1024, lb1 = w*1024 + 512;   // wave-uniform LDS bases (ush)

#define GLL(GP, LIDX) __builtin_amdgcn_global_load_lds( \
    (const __attribute__((address_space(1))) unsigned int*)(GP), \
    (__attribute__((address_space(3))) unsigned int*)(&SMEM[LIDX]), 16, 0, 0)

#define ISSUE_PROJ(BUFO, KT) do{ \
    GLL(Aab + aoff0 + (KT), (BUFO) + lb0); \
    GLL(Aab + aoff1 + (KT), (BUFO) + lb1); \
    GLL(Bhb + aoff0 + (KT), (BUFO) + 4096 + lb0); \
    GLL(Bhb + aoff1 + (KT), (BUFO) + 4096 + lb1); \
  }while(0)

  const int csw = (((4*(c & 1) + g) ^ ((c >> 1) & 7)) << 3);

  ISSUE_PROJ(0, 0);
  int cur = 0;
  for (int kt = 0; kt < DM; kt += 32){
    __syncthreads();                       // drains vmcnt -> buf[cur] ready
    if (kt + 32 < DM) ISSUE_PROJ((cur ^ 1)*8192, kt + 32);

    const ush* As  = SMEM + cur*8192;
    const ush* Bhs = As + 4096;

    bf8_t a_h[4];
    #pragma unroll
    for (int fm = 0; fm < 4; ++fm)
      a_h[fm] = *(const bf8_t*)&As[(32*wr + 8*fm + (c>>1))*64 + csw];
    __builtin_amdgcn_s_setprio(1);
    #pragma unroll
    for (int fn = 0; fn < 4; ++fn){
      bf8_t b_h = *(const bf8_t*)&Bhs[(32*wc + 8*fn + (c>>1))*64 + csw];
      #pragma unroll
      for (int fm = 0; fm < 4; ++fm)
        acc[fm][fn] = MFMA16(a_h[fm], b_h, acc[fm][fn]);
    }
    __builtin_amdgcn_s_setprio(0);
    cur ^= 1;
  }
#undef ISSUE_PROJ
#undef GLL

  if (z < 2){
    ush* O = (z==0) ? Qb : Kb;
    const float* bias = (z==0) ? bq : bk;
    #pragma unroll
    for (int fm = 0; fm < 4; ++fm){
      #pragma unroll
      for (int fn = 0; fn < 4; ++fn){
        const int col = n0 + 64*wc + 16*fn + c;
        const float bb = bias[col];
        const int row0 = m0 + 64*wr + 16*fm + 4*g;
        const int hd = col >> 6, d = col & 63;
        #pragma unroll
        for (int r = 0; r < 4; ++r){
          const int row = row0 + r;
          const int b = row >> 10, s = row & 1023;
          O[((size_t)(b*NH + hd)*SS + s)*DKH + d] = f2bf(acc[fm][fn][r] + bb);
        }
      }
    }
  } else {
    // V: transpose wave's 64(s) x 64(d) sub-tile through LDS -> coalesced (d,s)
    __syncthreads();                      // all waves done reading staging LDS
    ush* Vep = SMEM + w*4224;             // 64 rows(d) x 66 cols(s)
    #pragma unroll
    for (int fm = 0; fm < 4; ++fm){
      #pragma unroll
      for (int fn = 0; fn < 4; ++fn){
        const float bb = bv[n0 + 64*wc + 16*fn + c];
        #pragma unroll
        for (int r = 0; r < 4; ++r)
          Vep[(16*fn + c)*66 + 16*fm + 4*g + r] = f2bf(acc[fm][fn][r] + bb);
      }
    }
    const int b = m0 >> 10;
    const int s0 = (m0 & 1023) + 64*wr;
    const int hd = (n0 >> 6) + wc;
    const size_t vbase = ((size_t)(b*NH + hd))*DKH*SS;
    #pragma unroll
    for (int it = 0; it < 8; ++it){
      const int dr = 8*it + (lane >> 3);
      const int sc = (lane & 7)*8;
      uint4 vv = *(const uint4*)&Vep[dr*66 + sc];
      *(uint4*)&Vt[vbase + (size_t)dr*SS + s0 + sc] = vv;
    }
  }
}

// ---- output projection: C = A(bf16) @ Wo^T + bo, 128x64 tile, paired-row LDS
__global__ __launch_bounds__(256) void gemm_out(
    const ush* __restrict__ Abf, const ush* __restrict__ Bth,
    const float* __restrict__ bias, float* __restrict__ outf)
{
  __shared__ ush As[4096], Bs[2048];

  const int fid = blockIdx.x;
  const int glob = (fid & 7)*64 + (fid >> 3);
  const int m0 = (glob >> 4)*128, n0 = (glob & 15)*64;

  const int tid = threadIdx.x;
  const int lane = tid & 63, w = tid >> 6;
  const int c = lane & 15, g = lane >> 4;
  const int wr = w >> 1, wc = w & 1;

  f32x4 acc[4][2];
  #pragma unroll
  for (int i = 0; i < 4; ++i){ acc[i][0] = (f32x4){0,0,0,0}; acc[i][1] = (f32x4){0,0,0,0}; }

  const int prow = tid >> 3, ci = tid & 7;
  const int lr   = 2*prow + (ci >> 2);
  const int koff = (ci & 3) << 3;
  const int ws0  = prow*64 + ((ci ^ (prow & 7)) << 3);
  const int ws1  = ws0 + 32*64;
  const int csw  = (((4*(c & 1) + g) ^ ((c >> 1) & 7)) << 3);

  uint4 ar0, ar1, brr;
  #define ISSUE_OUT(KT) do{ \
    ar0 = *(const uint4*)(Abf + (size_t)(m0 + lr)*DM + (KT) + koff); \
    ar1 = *(const uint4*)(Abf + (size_t)(m0 + lr + 64)*DM + (KT) + koff); \
    brr = *(const uint4*)(Bth + (size_t)(n0 + lr)*DM + (KT) + koff); \
  }while(0)

  ISSUE_OUT(0);
  for (int kt = 0; kt < DM; kt += 32){
    *(uint4*)&As[ws0] = ar0;
    *(uint4*)&As[ws1] = ar1;
    if (lr < 64) *(uint4*)&Bs[ws0] = brr;
    __syncthreads();
    if (kt + 32 < DM) ISSUE_OUT(kt + 32);

    bf8_t a_h[4];
    #pragma unroll
    for (int fm = 0; fm < 4; ++fm)
      a_h[fm] = *(const bf8_t*)&As[(32*wr + 8*fm + (c>>1))*64 + csw];
    #pragma unroll
    for (int fn = 0; fn < 2; ++fn){
      bf8_t b_h = *(const bf8_t*)&Bs[(16*wc + 8*fn + (c>>1))*64 + csw];
      #pragma unroll
      for (int fm = 0; fm < 4; ++fm)
        acc[fm][fn] = MFMA16(a_h[fm], b_h, acc[fm][fn]);
    }
    __syncthreads();
  }
  #undef ISSUE_OUT

  #pragma unroll
  for (int fm = 0; fm < 4; ++fm){
    #pragma unroll
    for (int fn = 0; fn < 2; ++fn){
      const int col = n0 + 32*wc + 16*fn + c;
      const float bb = bias[col];
      const int row0 = m0 + 64*wr + 16*fm + 4*g;
      #pragma unroll
      for (int r = 0; r < 4; ++r)
        outf[(size_t)(row0 + r)*DM + col] = acc[fm][fn][r] + bb;
    }
  }
}

// ---- Stats pass: QBLK=128 (512 thr, 8 waves), KVBLK=64, 1-term QK (Qh),
// plain-bf16 Q/K, prefetch. Atomic partial sums only (no election).
__global__ __launch_bounds__(512) void attn_stats_mfma(
    const ush* __restrict__ Qb, const ush* __restrict__ Kb,
    float* __restrict__ stats)
{
  __shared__ ush Khs[64*64];
  __shared__ float red[8][3];
  const int tid = threadIdx.x, lane = tid & 63, w = tid >> 6;   // w 0..7
  const int c = lane & 15, g = lane >> 4;
  const int fid = blockIdx.x;
  const int glob = (fid & 7)*64 + (fid >> 3);     // 512 blocks, XCD-chunked
  const int bh = glob >> 3, q0 = (glob & 7)*128;

  bf8_t qh[2];
  {
    const ush* qp = Qb + ((size_t)bh*SS + q0 + 16*w + c)*DKH + 8*g;
    qh[0] = *(const bf8_t*)(qp);
    qh[1] = *(const bf8_t*)(qp + 32);
  }

  float ssum = 0.f, rmax = -1e30f, lsum = 0.f, l2sum = 0.f;
  const int rr0 = tid >> 3, ci = tid & 7;         // 64 rows x 8 chunks

  uint4 k0;
  #define ISSUE_ST(KC) do{ \
    k0 = *(const uint4*)(Kb + ((size_t)bh*SS + (KC)*64 + rr0)*DKH + ci*8); \
  }while(0)

  ISSUE_ST(0);
  for (int kc = 0; kc < 16; ++kc){
    *(uint4*)&Khs[swz8(rr0, ci)] = k0;
    __syncthreads();
    if (kc < 15) ISSUE_ST(kc + 1);

    f32x4 sa[4];
    #pragma unroll
    for (int fn = 0; fn < 4; ++fn) sa[fn] = (f32x4){0.f,0.f,0.f,0.f};
    __builtin_amdgcn_s_setprio(1);
    #pragma unroll
    for (int fn = 0; fn < 4; ++fn){
      #pragma unroll
      for (int ds = 0; ds < 2; ++ds){
        bf8_t ah = *(const bf8_t*)&Khs[swz8(16*fn + c, g + 4*ds)];
        sa[fn] = MFMA16(ah, qh[ds], sa[fn]);      // 1-term: Kh . Qh
      }
    }
    __builtin_amdgcn_s_setprio(0);
    #pragma unroll
    for (int fn = 0; fn < 4; ++fn){
      #pragma unroll
      for (int r = 0; r < 4; ++r){
        float s = sa[fn][r] * 0.125f;
        ssum += s;
        rmax = fmaxf(rmax, s);
        float e = exp2f(s * 0.7213475204f);       // exp(s/2); |s|<50 fp32-safe
        lsum += e;
        l2sum = fmaf(e, e, l2sum);
      }
    }
    __syncthreads();
  }
  #undef ISSUE_ST

  rmax  = fmaxf(rmax, __shfl_xor(rmax, 16, 64));
  rmax  = fmaxf(rmax, __shfl_xor(rmax, 32, 64));
  lsum  += __shfl_xor(lsum, 16, 64);   lsum  += __shfl_xor(lsum, 32, 64);
  l2sum += __shfl_xor(l2sum, 16, 64);  l2sum += __shfl_xor(l2sum, 32, 64);
  float varc = (l2sum/(lsum*lsum) - (1.0f/1024.f)) * (1.0f/1023.f);
  float a0 = ssum, a1 = rmax * 0.25f, a2 = varc * 0.25f;
  #pragma unroll
  for (int off = 1; off < 64; off <<= 1){
    a0 += __shfl_xor(a0, off, 64);
    a1 += __shfl_xor(a1, off, 64);
    a2 += __shfl_xor(a2, off, 64);
  }
  if (lane == 0){ red[w][0] = a0; red[w][1] = a1; red[w][2] = a2; }
  __syncthreads();
  if (tid == 0){
    float r0 = 0.f, r1 = 0.f, r2 = 0.f;
    #pragma unroll
    for (int i = 0; i < 8; ++i){ r0 += red[i][0]; r1 += red[i][1]; r2 += red[i][2]; }
    atomicAdd(&stats[bh*4+0], r0);
    atomicAdd(&stats[bh*4+1], r1);
    atomicAdd(&stats[bh*4+2], r2);
  }
}

// ---- Flash pass: QBLK=128 (512 thr), KVBLK=64 (16 iters), swapped QK^T
// 1-term (Kh . Qh), plain-bf16 Q/K, exp2, defer-max, swizzled LDS, prefetch.
// LDS = 32 KB. Time-MLP in prologue, lane-parallel + LDS broadcast.
__global__ __launch_bounds__(512) void attn_flash_mfma(
    const ush* __restrict__ Qb, const ush* __restrict__ Kb,
    const ush* __restrict__ Vt, const float* __restrict__ stats,
    const float* __restrict__ Wt1, const float* __restrict__ bt1,
    const float* __restrict__ Wt2, const float* __restrict__ bt2,
    ush* __restrict__ aout)
{
  __shared__ ush Khs[64*64], Vts[64*64], Ps[128*64];
  __shared__ float tshare;
  const int tid = threadIdx.x, lane = tid & 63, w = tid >> 6;   // w 0..7
  const int c = lane & 15, g = lane >> 4;
  const int fid = blockIdx.x;
  const int glob = (fid & 7)*64 + (fid >> 3);     // 512 blocks, XCD-chunked
  const int bh = glob >> 3, q0 = (glob & 7)*128;

  // ---- lane-parallel time-MLP: lane j of wave 0 computes hidden unit j
  if (tid < 16){
    float mean = fminf(fmaxf(stats[bh*4+0] * (1.f/(1024.f*1024.f)), -10.f), 10.f);
    float mx   = fminf(fmaxf(stats[bh*4+1] * (1.f/1024.f), -10.f), 10.f);
    float ent  = fminf(fmaxf(stats[bh*4+2] * (1.f/1024.f),   0.f),  1.f);
    float h = tanhf(mean*Wt1[tid] + mx*Wt1[16+tid] + ent*Wt1[32+tid] + bt1[tid])
              * Wt2[tid];
    h += __shfl_xor(h, 1, 64);
    h += __shfl_xor(h, 2, 64);
    h += __shfl_xor(h, 4, 64);
    h += __shfl_xor(h, 8, 64);
    if (tid == 0){
      float raw = h + bt2[0];
      float sig = 1.f / (1.f + expf(-raw));
      float t = 0.01f + sig * 1.99f;
      t = fminf(fminf(fmaxf(t, 0.01f), 2.0f), 0.85f);
      tshare = (0.5f / t) * 1.44269504f;          // exp2 domain
    }
  }

  bf8_t qh[2];
  {
    const ush* qp = Qb + ((size_t)bh*SS + q0 + 16*w + c)*DKH + 8*g;
    qh[0] = *(const bf8_t*)(qp);
    qh[1] = *(const bf8_t*)(qp + 32);
  }

  f32x4 o[4];
  #pragma unroll
  for (int i = 0; i < 4; ++i) o[i] = (f32x4){0.f,0.f,0.f,0.f};
  float m = -INFINITY, lpart = 0.f;

  const int rr0 = tid >> 3, ci = tid & 7;         // 64 rows x 8 chunks

  uint4 k0, vr0;
  #define ISSUE_FL(KC) do{ \
    k0  = *(const uint4*)(Kb + ((size_t)bh*SS + (KC)*64 + rr0)*DKH + ci*8); \
    vr0 = *(const uint4*)(Vt + ((size_t)bh*DKH + rr0)*SS + (KC)*64 + ci*8); \
  }while(0)

  ISSUE_FL(0);
  *(uint4*)&Khs[swz8(rr0, ci)] = k0;
  *(uint4*)&Vts[swz8(rr0, ci)] = vr0;
  __syncthreads();                                 // staging + tshare visible
  const float tsc2 = tshare;

  for (int kc = 0; kc < 16; ++kc){
    if (kc){
      *(uint4*)&Khs[swz8(rr0, ci)] = k0;
      *(uint4*)&Vts[swz8(rr0, ci)] = vr0;
      __syncthreads();
    }
    if (kc < 15) ISSUE_FL(kc + 1);

    f32x4 sa[4];
    #pragma unroll
    for (int fn = 0; fn < 4; ++fn) sa[fn] = (f32x4){0.f,0.f,0.f,0.f};
    __builtin_amdgcn_s_setprio(1);
    #pragma unroll
    for (int fn = 0; fn < 4; ++fn){
      #pragma unroll
      for (int ds = 0; ds < 2; ++ds){
        bf8_t ah = *(const bf8_t*)&Khs[swz8(16*fn + c, g + 4*ds)];
        sa[fn] = MFMA16(ah, qh[ds], sa[fn]);   // 1-term: Kh . Qh
      }
    }
    __builtin_amdgcn_s_setprio(0);

    // lane-local max over own 16 kv; shuffles only in the rare rescale path
    float pmaxr = -1e30f;
    #pragma unroll
    for (int fn = 0; fn < 4; ++fn)
      #pragma unroll
      for (int r = 0; r < 4; ++r) pmaxr = fmaxf(pmaxr, sa[fn][r]);

    if (!__all(pmaxr * tsc2 <= m + 30.f)){     // fires ~once (kc=0)
      pmaxr = fmaxf(pmaxr, __shfl_xor(pmaxr, 16, 64));
      pmaxr = fmaxf(pmaxr, __shfl_xor(pmaxr, 32, 64));
      float pmax = pmaxr * tsc2;
      float mn = fmaxf(m, pmax);
      float sc = exp2f(m - mn);
      m = mn;
      lpart *= sc;
      #pragma unroll
      for (int r = 0; r < 4; ++r){
        float so = __shfl(sc, 4*g + r, 16);    // sc of q-row 4g+r (c'=4g+r)
        #pragma unroll
        for (int fn = 0; fn < 4; ++fn) o[fn][r] *= so;
      }
    }

    const float mneg = -m;
    #pragma unroll
    for (int fn = 0; fn < 4; ++fn){
      float e0 = exp2f(fmaf(sa[fn][0], tsc2, mneg));
      float e1 = exp2f(fmaf(sa[fn][1], tsc2, mneg));
      float e2 = exp2f(fmaf(sa[fn][2], tsc2, mneg));
      float e3 = exp2f(fmaf(sa[fn][3], tsc2, mneg));
      lpart += (e0 + e1) + (e2 + e3);
      uint2 pk;
      pk.x = pk2(e0, e1);
      pk.y = pk2(e2, e3);
      const int q4 = 4*fn + g;
      const int addr = (16*w + c)*64 + ((((q4 >> 1) ^ (c & 7)) << 3)) + (q4 & 1)*4;
      *(uint2*)&Ps[addr] = pk;
    }

    __builtin_amdgcn_s_setprio(1);
    #pragma unroll
    for (int kvs = 0; kvs < 2; ++kvs){
      bf8_t pa = *(const bf8_t*)&Ps[swz8(16*w + c, g + 4*kvs)];
      #pragma unroll
      for (int fn = 0; fn < 4; ++fn){
        bf8_t vb = *(const bf8_t*)&Vts[swz8(16*fn + c, g + 4*kvs)];
        o[fn] = MFMA16(pa, vb, o[fn]);
      }
    }
    __builtin_amdgcn_s_setprio(0);
    __syncthreads();
  }
  #undef ISSUE_FL

  lpart += __shfl_xor(lpart, 16, 64);
  lpart += __shfl_xor(lpart, 32, 64);
  const int b = bh >> 4, hd = bh & 15;
  #pragma unroll
  for (int r = 0; r < 4; ++r){
    float linv = 1.f / __shfl(lpart, 4*g + r, 16);   // l of q-row 4g+r
    const int q = q0 + 16*w + 4*g + r;
    #pragma unroll
    for (int fn = 0; fn < 4; ++fn)
      aout[((size_t)(b*SS + q))*DM + hd*DKH + 16*fn + c] = f2bf(o[fn][r] * linv);
  }
}

extern "C" void kernel_launch(void* const* d_in, const int* in_sizes, int n_in,
                              void* d_out, int out_size, void* d_ws, size_t ws_size,
                              hipStream_t stream)
{
  const float* query = (const float*)d_in[0];
  const float* key   = (const float*)d_in[1];
  const float* value = (const float*)d_in[2];
  const float* Wq = (const float*)d_in[3];
  const float* bq = (const float*)d_in[4];
  const float* Wk = (const float*)d_in[5];
  const float* bk = (const float*)d_in[6];
  const float* Wv = (const float*)d_in[7];
  const float* bv = (const float*)d_in[8];
  const float* Wo = (const float*)d_in[9];
  const float* bo = (const float*)d_in[10];
  const float* Wt1 = (const float*)d_in[11];
  const float* bt1 = (const float*)d_in[12];
  const float* Wt2 = (const float*)d_in[13];
  const float* bt2 = (const float*)d_in[14];

  const size_t E = (size_t)NB*SS*DM;       // 4,194,304
  const size_t WE = (size_t)DM*DM;

  ush* Qbb = (ush*)d_ws;                   // E ush (plain bf16)
  ush* Kbb = Qbb + E;                      // E ush
  ush* Vtb = Kbb + E;                      // E ush (b*16+h, dk, s)
  ush* Aob = Vtb + E;                      // E ush  -- also aliased as xqb
  ush* xqb = Aob;                          // alias: consumed before Aob written
  ush* xkb = Aob + E;
  ush* xvb = xkb + E;
  ush* Wqh = xvb + E;
  ush* Wkh = Wqh + WE;
  ush* Wvh = Wkh + WE;
  ush* Woh = Wvh + WE;
  float* stats = (float*)(Woh + WE);       // 256 floats

  hipMemsetAsync(stats, 0, 4*NBH*sizeof(float), stream);

  xconv<<<dim3(2048, 3), 256, 0, stream>>>(query, key, value, xqb, xkb, xvb);

  dim3 wb(32, 8), wg(32, 32, 4);
  wconv4<<<wg, wb, 0, stream>>>(Wq, Wk, Wv, Wo, Wqh, Wkh, Wvh, Woh);

  proj_qkv<<<768, 256, 0, stream>>>(xqb, xkb, xvb,
      Wqh, Wkh, Wvh, bq, bk, bv, Qbb, Kbb, Vtb);

  attn_stats_mfma<<<512, 512, 0, stream>>>(Qbb, Kbb, stats);
  attn_flash_mfma<<<512, 512, 0, stream>>>(Qbb, Kbb, Vtb, stats,
      Wt1, bt1, Wt2, bt2, Aob);

  gemm_out<<<512, 256, 0, stream>>>(Aob, Woh, bo, (float*)d_out);
}